// Round 2
// baseline (1047.730 us; speedup 1.0000x reference)
//
#include <hip/hip_runtime.h>
#include <stdint.h>

// ContextualAttention on MI355X. Inputs/outputs are float32 (per reference).
// Internals: split-bf16 (hi/lo) MFMA for the correlation GEMM (fp32-grade logits),
// plain bf16 MFMA for deconv + final convs, fp32 fuse/softmax.
//
// Pipeline:
//   build_wn:  normalized 3x3 patch bank Wn[item][o][1728]  (bf16 hi|hi|lo)
//   build_x:   im2col of fd X[item][s][1728]                (bf16 hi|lo|hi)
//   gemm_corr: Y[o][s] = Wn @ X^T  (K=1728 -> exact 3 cross terms) -> Buf1 f32
//   fuse1:     Z1[a][b] = sum_d Y[a+d][b+d]                        -> Buf2
//   fuse2p:    S[o][s] = sum_d Z1[g(o,d)][g(s,d)], g=tau(tau(x)+d) -> Buf1
//   transp:    St[s][o] = S[o][s]                                  -> Buf2
//   softmax:   P over o, scale 10; padded Pt2[(sy+1)*50+sx+1][o] bf16
//   build_rwa: 4x4 raw patch bank rw_a[item][tap16][co][l] bf16
//   deconv:    per (item,phase): y[co][s'] via MFMA, /4            -> Yb bf16
//   im2col + conv GEMM (M=64) x2 with bias -> d_out f32
//
// ws layout (bytes), total 2*84,934,656 = 169,869,312:
//   A=[0, 84934656):      Buf1 f32; later Pt2(46,080,000)+Rwa(18,874,368)
//                         +Yb(@64,954,368, 4,718,592)+Y1(@69,672,960, 4,718,592)
//   B=[84934656, 2x):     Wn(31,850,496)+Xb(31,850,496); later Buf2 f32; later X2(42,467,328)

#define SZ_BUF 84934656ull
typedef __attribute__((ext_vector_type(8))) short short8;
typedef __attribute__((ext_vector_type(4))) float f32x4;

__device__ __forceinline__ float b2f(uint16_t u){
  union { uint32_t i; float f; } v; v.i = ((uint32_t)u) << 16; return v.f;
}
__device__ __forceinline__ uint16_t f2b(float f){
  uint32_t x = __float_as_uint(f);
  uint32_t r = (x + 0x7FFFu + ((x >> 16) & 1u)) >> 16;
  return (uint16_t)r;
}
__device__ __forceinline__ int gfun(int x, int d){
  int t = (x % 48) * 48 + (x / 48) + d;
  if ((unsigned)t >= 2304u) return -1;
  return (t % 48) * 48 + (t / 48);
}

// ---------------- prep kernels ----------------

__global__ void k_build_wn(const float* __restrict__ bsrc, uint16_t* __restrict__ wn){
  int o = blockIdx.x, item = blockIdx.y, c = threadIdx.x;
  int m = o * 64 + c;
  int c0 = m / 2304, rem = m % 2304, i = rem / 48, j = rem % 48;
  const float* bp = bsrc + ((size_t)item * 64 + c0) * 9216;
  float v[9]; float ss = 0.f;
#pragma unroll
  for (int p = 0; p < 3; p++)
#pragma unroll
    for (int q = 0; q < 3; q++){
      int y = i + p - 1, x = j + q - 1;
      float val = 0.f;
      if ((unsigned)y < 48u && (unsigned)x < 48u) val = bp[y * 192 + x * 2];
      v[p * 3 + q] = val; ss += val * val;
    }
#pragma unroll
  for (int off = 32; off > 0; off >>= 1) ss += __shfl_xor(ss, off, 64);
  float inv = 1.f / fmaxf(sqrtf(ss), 1e-4f);
  uint16_t* wr = wn + ((size_t)item * 2304 + o) * 1728;
#pragma unroll
  for (int t = 0; t < 9; t++){
    float fv = v[t] * inv;
    uint16_t hi = f2b(fv);
    uint16_t lo = f2b(fv - b2f(hi));
    wr[c * 9 + t] = hi;            // block 0: a_hi
    wr[576 + c * 9 + t] = hi;      // block 1: a_hi (pairs with b_lo)
    wr[1152 + c * 9 + t] = lo;     // block 2: a_lo (pairs with b_hi)
  }
}

__global__ void k_build_x(const float* __restrict__ fsrc, uint16_t* __restrict__ xb){
  int s = blockIdx.x, item = blockIdx.y, c = threadIdx.x;
  int y = s / 48, x = s % 48;
  const float* fp = fsrc + ((size_t)item * 64 + c) * 9216;
  uint16_t* xr = xb + ((size_t)item * 2304 + s) * 1728;
#pragma unroll
  for (int p = 0; p < 3; p++)
#pragma unroll
    for (int q = 0; q < 3; q++){
      int yy = y + p - 1, xx = x + q - 1;
      float val = 0.f;
      if ((unsigned)yy < 48u && (unsigned)xx < 48u) val = fp[yy * 192 + xx * 2];
      uint16_t hi = f2b(val);
      uint16_t lo = f2b(val - b2f(hi));
      int t = p * 3 + q;
      xr[c * 9 + t] = hi;           // block 0: b_hi
      xr[576 + c * 9 + t] = lo;     // block 1: b_lo
      xr[1152 + c * 9 + t] = hi;    // block 2: b_hi
    }
}

// ---------------- correlation GEMM: Y[o][s], M=N=2304, K=1728 ----------------

__launch_bounds__(256)
__global__ void k_gemm_corr(const uint16_t* __restrict__ A, const uint16_t* __restrict__ B,
                            float* __restrict__ Cd){
  __shared__ __align__(16) uint16_t As[128 * 32];
  __shared__ __align__(16) uint16_t Bs[128 * 32];
  int item = blockIdx.z;
  int n0 = blockIdx.x * 128, m0 = blockIdx.y * 128;
  const uint16_t* Ap = A + (size_t)item * 2304 * 1728;
  const uint16_t* Bp = B + (size_t)item * 2304 * 1728;
  int tid = threadIdx.x;
  int wave = tid >> 6, lane = tid & 63, lm = lane & 15, lg = lane >> 4;
  int wy = wave >> 1, wx = wave & 1;
  f32x4 acc[4][4] = {};
  for (int kt = 0; kt < 54; kt++){
    int kb = kt * 32;
#pragma unroll
    for (int c = tid; c < 1024; c += 256){
      int half = c >> 9;
      int cc = c & 511;
      int row = cc >> 2, col = (cc & 3) * 8;
      if (half == 0)
        *(short8*)&As[row * 32 + col] = *(const short8*)&Ap[(size_t)(m0 + row) * 1728 + kb + col];
      else
        *(short8*)&Bs[row * 32 + col] = *(const short8*)&Bp[(size_t)(n0 + row) * 1728 + kb + col];
    }
    __syncthreads();
    short8 af[4], bf[4];
#pragma unroll
    for (int i = 0; i < 4; i++){
      af[i] = *(const short8*)&As[(wy * 64 + i * 16 + lm) * 32 + lg * 8];
      bf[i] = *(const short8*)&Bs[(wx * 64 + i * 16 + lm) * 32 + lg * 8];
    }
#pragma unroll
    for (int i = 0; i < 4; i++)
#pragma unroll
      for (int j = 0; j < 4; j++)
        acc[i][j] = __builtin_amdgcn_mfma_f32_16x16x32_bf16(af[i], bf[j], acc[i][j], 0, 0, 0);
    __syncthreads();
  }
  float* Cp = Cd + (size_t)item * 2304 * 2304;
#pragma unroll
  for (int i = 0; i < 4; i++){
    int rb = m0 + wy * 64 + i * 16 + lg * 4;
#pragma unroll
    for (int j = 0; j < 4; j++){
      int cc = n0 + wx * 64 + j * 16 + lm;
#pragma unroll
      for (int r = 0; r < 4; r++)
        Cp[(size_t)(rb + r) * 2304 + cc] = acc[i][j][r];
    }
  }
}

// ---------------- fuse / permute / softmax ----------------

__global__ void k_fuse1(const float* __restrict__ in, float* __restrict__ out){
  int a = blockIdx.x, item = blockIdx.y;
  const float* ip = in + (size_t)item * 2304 * 2304;
  float* op = out + (size_t)item * 2304 * 2304;
  const float* r0 = ip + (size_t)a * 2304;
  for (int b = threadIdx.x; b < 2304; b += 256){
    float s = r0[b];
    if (a > 0 && b > 0) s += r0[b - 2305];
    if (a < 2303 && b < 2303) s += r0[b + 2305];
    op[(size_t)a * 2304 + b] = s;
  }
}

__global__ void k_fuse2p(const float* __restrict__ z1, float* __restrict__ sout){
  int o = blockIdx.x, item = blockIdx.y;
  const float* ip = z1 + (size_t)item * 2304 * 2304;
  float* op = sout + (size_t)item * 2304 * 2304 + (size_t)o * 2304;
  int r[3];
  r[0] = gfun(o, -1); r[1] = o; r[2] = gfun(o, 1);
  for (int s = threadIdx.x; s < 2304; s += 256){
    float acc = 0.f;
#pragma unroll
    for (int d = 0; d < 3; d++){
      if (r[d] < 0) continue;
      int cc = gfun(s, d - 1);
      if (cc < 0) continue;
      acc += ip[(size_t)r[d] * 2304 + cc];
    }
    op[s] = acc;
  }
}

__global__ void k_transp(const float* __restrict__ in, float* __restrict__ out){
  __shared__ float tile[32][33];
  int item = blockIdx.z;
  const float* ip = in + (size_t)item * 2304 * 2304;
  float* op = out + (size_t)item * 2304 * 2304;
  int x0 = blockIdx.x * 32, y0 = blockIdx.y * 32;
  int tx = threadIdx.x, ty = threadIdx.y;
  for (int r = ty; r < 32; r += 8) tile[r][tx] = ip[(size_t)(y0 + r) * 2304 + x0 + tx];
  __syncthreads();
  for (int r = ty; r < 32; r += 8) op[(size_t)(x0 + r) * 2304 + y0 + tx] = tile[tx][r];
}

__global__ void k_softmax(const float* __restrict__ st, uint16_t* __restrict__ pt2){
  __shared__ float red[4];
  int s = blockIdx.x, item = blockIdx.y, t = threadIdx.x;
  const float* row = st + ((size_t)item * 2304 + s) * 2304;
  float v[9]; float mx = -3.4e38f;
#pragma unroll
  for (int u = 0; u < 9; u++){ v[u] = row[t + u * 256]; mx = fmaxf(mx, v[u]); }
#pragma unroll
  for (int off = 32; off > 0; off >>= 1) mx = fmaxf(mx, __shfl_xor(mx, off, 64));
  if ((t & 63) == 0) red[t >> 6] = mx;
  __syncthreads();
  mx = fmaxf(fmaxf(red[0], red[1]), fmaxf(red[2], red[3]));
  float sum = 0.f;
#pragma unroll
  for (int u = 0; u < 9; u++){ v[u] = __expf(10.f * (v[u] - mx)); sum += v[u]; }
#pragma unroll
  for (int off = 32; off > 0; off >>= 1) sum += __shfl_xor(sum, off, 64);
  __syncthreads();
  if ((t & 63) == 0) red[t >> 6] = sum;
  __syncthreads();
  float inv = 1.f / (red[0] + red[1] + red[2] + red[3]);
  uint16_t* pr = pt2 + ((size_t)item * 2500 + (size_t)(s / 48 + 1) * 50 + (s % 48) + 1) * 2304;
#pragma unroll
  for (int u = 0; u < 9; u++) pr[t + u * 256] = f2b(v[u] * inv);
}

// ---------------- raw 4x4 patch bank, layout [item][tap16][co][l] ----------------

__global__ void k_build_rwa(const float* __restrict__ bsrc, uint16_t* __restrict__ rwa){
  __shared__ uint16_t tile[64][66];
  int item = blockIdx.y, l0 = blockIdx.x * 64;
  const float* bp = bsrc + (size_t)item * 64 * 9216;
  int wave = threadIdx.x >> 6, lane = threadIdx.x & 63;
  for (int tap = 0; tap < 16; tap++){
    int py = tap >> 2, qx = tap & 3;
#pragma unroll
    for (int step = 0; step < 16; step++){
      int lsub = wave * 16 + step;
      int l = l0 + lsub, co = lane;
      int m = l * 64 + co;
      int c0 = m / 2304, rem = m % 2304, i = rem / 48, jj = rem % 48;
      int Y = 2 * i + py - 1, X = 2 * jj + qx - 1;
      float val = 0.f;
      if ((unsigned)Y < 96u && (unsigned)X < 96u) val = bp[(size_t)c0 * 9216 + Y * 96 + X];
      tile[lsub][co] = f2b(val);
    }
    __syncthreads();
#pragma unroll
    for (int step = 0; step < 16; step++){
      int co = wave * 16 + step;
      rwa[(((size_t)item * 16 + tap) * 64 + co) * 2304 + l0 + lane] = tile[lane][co];
    }
    __syncthreads();
  }
}

// ---------------- deconv (transposed conv) as MFMA GEMM per (item, phase) ----------------

__launch_bounds__(256)
__global__ void k_deconv(const uint16_t* __restrict__ rwa, const uint16_t* __restrict__ pt2,
                         uint16_t* __restrict__ yout){
  __shared__ __align__(16) uint16_t As[64 * 32];
  __shared__ __align__(16) uint16_t Bs[128 * 32];
  int n0 = blockIdx.x * 128, phase = blockIdx.y, item = blockIdx.z;
  int fy = phase >> 1, fx = phase & 1;
  int tid = threadIdx.x, wave = tid >> 6, lane = tid & 63, lm = lane & 15, lg = lane >> 4;
  const uint16_t* Pp = pt2 + (size_t)item * 2500 * 2304;
  const uint16_t* Rp = rwa + (size_t)item * 16 * 64 * 2304;
  f32x4 acc[4][2] = {};
  for (int tap = 0; tap < 4; tap++){
    int ay = tap >> 1, ax = tap & 1;
    int py = 3 - fy - 2 * ay, qx = 3 - fx - 2 * ax;
    const uint16_t* Ap = Rp + (size_t)(py * 4 + qx) * 64 * 2304;
    for (int kt = 0; kt < 72; kt++){
      int kb = kt * 32;
#pragma unroll
      for (int c = tid; c < 768; c += 256){
        if (c < 256){
          int row = c >> 2, col = (c & 3) * 8;
          *(short8*)&As[row * 32 + col] = *(const short8*)&Ap[(size_t)row * 2304 + kb + col];
        } else {
          int cc = c - 256; int row = cc >> 2, col = (cc & 3) * 8;
          int n = n0 + row; int my = n / 48, mx = n % 48;
          int prow = (my + ay + fy) * 50 + (mx + ax + fx);
          *(short8*)&Bs[row * 32 + col] = *(const short8*)&Pp[(size_t)prow * 2304 + kb + col];
        }
      }
      __syncthreads();
      short8 af[4], bf[2];
#pragma unroll
      for (int i = 0; i < 4; i++) af[i] = *(const short8*)&As[(i * 16 + lm) * 32 + lg * 8];
#pragma unroll
      for (int j = 0; j < 2; j++) bf[j] = *(const short8*)&Bs[(wave * 32 + j * 16 + lm) * 32 + lg * 8];
#pragma unroll
      for (int i = 0; i < 4; i++)
#pragma unroll
        for (int j = 0; j < 2; j++)
          acc[i][j] = __builtin_amdgcn_mfma_f32_16x16x32_bf16(af[i], bf[j], acc[i][j], 0, 0, 0);
      __syncthreads();
    }
  }
  uint16_t* yp = yout + (size_t)item * 64 * 9216;
#pragma unroll
  for (int i = 0; i < 4; i++)
#pragma unroll
    for (int j = 0; j < 2; j++){
      int n = n0 + wave * 32 + j * 16 + lm;
      int my = n / 48, mx = n % 48;
      int Y = 2 * my + fy, X = 2 * mx + fx;
#pragma unroll
      for (int r = 0; r < 4; r++){
        int co = i * 16 + lg * 4 + r;
        yp[(size_t)co * 9216 + Y * 96 + X] = f2b(acc[i][j][r] * 0.25f);
      }
    }
}

// ---------------- final 3x3 convs ----------------

__global__ void k_im2col(const uint16_t* __restrict__ src, uint16_t* __restrict__ dst){
  int pix = blockIdx.x, item = blockIdx.y, ci = threadIdx.x;
  int y = pix / 96, x = pix % 96;
  const uint16_t* sp = src + ((size_t)item * 64 + ci) * 9216;
  uint16_t* dr = dst + ((size_t)item * 9216 + pix) * 576 + ci * 9;
#pragma unroll
  for (int p = 0; p < 3; p++)
#pragma unroll
    for (int q = 0; q < 3; q++){
      int yy = y + p - 1, xx = x + q - 1;
      dr[p * 3 + q] = ((unsigned)yy < 96u && (unsigned)xx < 96u) ? sp[yy * 96 + xx] : (uint16_t)0;
    }
}

__launch_bounds__(256)
__global__ void k_conv_gemm(const float* __restrict__ A, const uint16_t* __restrict__ B,
                            const float* __restrict__ bias,
                            uint16_t* __restrict__ dst16, float* __restrict__ dst32){
  __shared__ __align__(16) uint16_t As[64 * 32];
  __shared__ __align__(16) uint16_t Bs[128 * 32];
  int n0 = blockIdx.x * 128, item = blockIdx.z;
  int tid = threadIdx.x, wave = tid >> 6, lane = tid & 63, lm = lane & 15, lg = lane >> 4;
  const uint16_t* Bp = B + (size_t)item * 9216 * 576;
  f32x4 acc[4][2] = {};
  for (int kt = 0; kt < 18; kt++){
    int kb = kt * 32;
#pragma unroll
    for (int c = tid; c < 768; c += 256){
      if (c < 256){
        int row = c >> 2, col = (c & 3) * 8;
        const float* srcp = &A[(size_t)row * 576 + kb + col];
        short8 h;
#pragma unroll
        for (int u = 0; u < 8; u++) h[u] = (short)f2b(srcp[u]);
        *(short8*)&As[row * 32 + col] = h;
      } else {
        int cc = c - 256; int row = cc >> 2, col = (cc & 3) * 8;
        *(short8*)&Bs[row * 32 + col] = *(const short8*)&Bp[(size_t)(n0 + row) * 576 + kb + col];
      }
    }
    __syncthreads();
    short8 af[4], bf[2];
#pragma unroll
    for (int i = 0; i < 4; i++) af[i] = *(const short8*)&As[(i * 16 + lm) * 32 + lg * 8];
#pragma unroll
    for (int j = 0; j < 2; j++) bf[j] = *(const short8*)&Bs[(wave * 32 + j * 16 + lm) * 32 + lg * 8];
#pragma unroll
    for (int i = 0; i < 4; i++)
#pragma unroll
      for (int j = 0; j < 2; j++)
        acc[i][j] = __builtin_amdgcn_mfma_f32_16x16x32_bf16(af[i], bf[j], acc[i][j], 0, 0, 0);
    __syncthreads();
  }
#pragma unroll
  for (int i = 0; i < 4; i++)
#pragma unroll
    for (int j = 0; j < 2; j++){
      int n = n0 + wave * 32 + j * 16 + lm;
#pragma unroll
      for (int r = 0; r < 4; r++){
        int co = i * 16 + lg * 4 + r;
        float val = acc[i][j][r] + bias[co];
        if (dst32) dst32[((size_t)item * 64 + co) * 9216 + n] = val;
        else       dst16[((size_t)item * 64 + co) * 9216 + n] = f2b(val);
      }
    }
}

// ---------------- launch ----------------

extern "C" void kernel_launch(void* const* d_in, const int* in_sizes, int n_in,
                              void* d_out, int out_size, void* d_ws, size_t ws_size,
                              hipStream_t stream){
  const float* f  = (const float*)d_in[0];
  const float* b  = (const float*)d_in[1];
  const float* w1 = (const float*)d_in[2];
  const float* b1 = (const float*)d_in[3];
  const float* w2 = (const float*)d_in[4];
  const float* b2 = (const float*)d_in[5];
  char* ws = (char*)d_ws;
  float*    Buf1 = (float*)ws;
  float*    Buf2 = (float*)(ws + SZ_BUF);
  uint16_t* Wn   = (uint16_t*)(ws + SZ_BUF);
  uint16_t* Xb   = Wn + (size_t)4 * 2304 * 1728;
  uint16_t* Pt2  = (uint16_t*)ws;                      // 46,080,000 B
  uint16_t* Rwa  = (uint16_t*)(ws + 46080000ull);      // 18,874,368 B
  uint16_t* Yb   = (uint16_t*)(ws + 64954368ull);      //  4,718,592 B
  uint16_t* Y1   = (uint16_t*)(ws + 69672960ull);      //  4,718,592 B
  uint16_t* X2   = (uint16_t*)(ws + SZ_BUF);           // 42,467,328 B (over Buf2)
  float*    out  = (float*)d_out;

  k_build_wn<<<dim3(2304, 4), 64, 0, stream>>>(b, Wn);
  k_build_x<<<dim3(2304, 4), 64, 0, stream>>>(f, Xb);
  k_gemm_corr<<<dim3(18, 18, 4), 256, 0, stream>>>(Wn, Xb, Buf1);
  k_fuse1<<<dim3(2304, 4), 256, 0, stream>>>(Buf1, Buf2);
  k_fuse2p<<<dim3(2304, 4), 256, 0, stream>>>(Buf2, Buf1);
  k_transp<<<dim3(72, 72, 4), dim3(32, 8), 0, stream>>>(Buf1, Buf2);
  hipMemsetAsync(Pt2, 0, (size_t)4 * 2500 * 2304 * 2, stream);
  k_build_rwa<<<dim3(36, 4), 256, 0, stream>>>(b, Rwa);
  k_softmax<<<dim3(2304, 4), 256, 0, stream>>>(Buf2, Pt2);
  k_deconv<<<dim3(18, 4, 4), 256, 0, stream>>>(Rwa, Pt2, Yb);
  k_im2col<<<dim3(9216, 4), 64, 0, stream>>>(Yb, X2);
  k_conv_gemm<<<dim3(72, 1, 4), 256, 0, stream>>>(w1, X2, b1, Y1, nullptr);
  k_im2col<<<dim3(9216, 4), 64, 0, stream>>>(Y1, X2);
  k_conv_gemm<<<dim3(72, 1, 4), 256, 0, stream>>>(w2, X2, b2, nullptr, out);
}

// Round 3
// 810.647 us; speedup vs baseline: 1.2925x; 1.2925x over previous
//
#include <hip/hip_runtime.h>
#include <stdint.h>

// ContextualAttention on MI355X. Inputs/outputs float32; internals split-bf16 MFMA
// for correlation logits, plain bf16 MFMA elsewhere, fp32 fuse/softmax.
//
// Round 3 changes:
//  - deconv split-K over ay tap-half: grid(18,2,16), fp32 partials (no atomics) + k_dred
//  - global_load_lds width=16 staging in all MFMA kernels (m97 pattern)
//  - fuse1+fuse2p+transp merged into single 9-gather kernel k_fuse
//  - w1/w2 prepacked to bf16 (k_pack_w)
//
// ws layout (bytes), total 169,869,312:
//  region A [0, 84934656):
//    phase1: Buf1 f32 (85 MB, corr logits)
//    phase2: Pt2 bf16 [0, 46080000) | Rwa [46080000, 64954368) | Yb [64954368, 69672960)
//            | Y1 [69672960, 74391552) | Wp1 [74391552, +73728) | Wp2 [74465280, +73728)
//  region B [84934656, 169869312):
//    phase1: Wn (31850496) + Xb (31850496)
//    phase2: Buf2 f32 (St, 85 MB)
//    phase3: Part f32 2x37748736 = 75497472
//    phase4: X2 (42467328)

#define SZ_BUF 84934656ull
typedef __attribute__((ext_vector_type(8))) short short8;
typedef __attribute__((ext_vector_type(4))) float f32x4;

#if defined(__has_builtin)
#if __has_builtin(__builtin_amdgcn_global_load_lds)
#define HAVE_GLL 1
#endif
#endif

#ifdef HAVE_GLL
typedef const __attribute__((address_space(1))) void* gp1_t;
typedef __attribute__((address_space(3))) void* lp3_t;
__device__ __forceinline__ void gl_lds16(const void* g, void* l){
  __builtin_amdgcn_global_load_lds((gp1_t)g, (lp3_t)l, 16, 0, 0);
}
#else
__device__ __forceinline__ void gl_lds16(const void* g, void* l){
  *(short8*)l = *(const short8*)g;
}
#endif

__device__ __forceinline__ float b2f(uint16_t u){
  union { uint32_t i; float f; } v; v.i = ((uint32_t)u) << 16; return v.f;
}
__device__ __forceinline__ uint16_t f2b(float f){
  uint32_t x = __float_as_uint(f);
  uint32_t r = (x + 0x7FFFu + ((x >> 16) & 1u)) >> 16;
  return (uint16_t)r;
}
__device__ __forceinline__ int gfun(int x, int d){
  int t = (x % 48) * 48 + (x / 48) + d;
  if ((unsigned)t >= 2304u) return -1;
  return (t % 48) * 48 + (t / 48);
}

// ---------------- prep kernels ----------------

__global__ void k_build_wn(const float* __restrict__ bsrc, uint16_t* __restrict__ wn){
  int o = blockIdx.x, item = blockIdx.y, c = threadIdx.x;
  int m = o * 64 + c;
  int c0 = m / 2304, rem = m % 2304, i = rem / 48, j = rem % 48;
  const float* bp = bsrc + ((size_t)item * 64 + c0) * 9216;
  float v[9]; float ss = 0.f;
#pragma unroll
  for (int p = 0; p < 3; p++)
#pragma unroll
    for (int q = 0; q < 3; q++){
      int y = i + p - 1, x = j + q - 1;
      float val = 0.f;
      if ((unsigned)y < 48u && (unsigned)x < 48u) val = bp[y * 192 + x * 2];
      v[p * 3 + q] = val; ss += val * val;
    }
#pragma unroll
  for (int off = 32; off > 0; off >>= 1) ss += __shfl_xor(ss, off, 64);
  float inv = 1.f / fmaxf(sqrtf(ss), 1e-4f);
  uint16_t* wr = wn + ((size_t)item * 2304 + o) * 1728;
#pragma unroll
  for (int t = 0; t < 9; t++){
    float fv = v[t] * inv;
    uint16_t hi = f2b(fv);
    uint16_t lo = f2b(fv - b2f(hi));
    wr[c * 9 + t] = hi;            // block 0: a_hi (x b_hi)
    wr[576 + c * 9 + t] = hi;      // block 1: a_hi (x b_lo)
    wr[1152 + c * 9 + t] = lo;     // block 2: a_lo (x b_hi)
  }
}

__global__ void k_build_x(const float* __restrict__ fsrc, uint16_t* __restrict__ xb){
  int s = blockIdx.x, item = blockIdx.y, c = threadIdx.x;
  int y = s / 48, x = s % 48;
  const float* fp = fsrc + ((size_t)item * 64 + c) * 9216;
  uint16_t* xr = xb + ((size_t)item * 2304 + s) * 1728;
#pragma unroll
  for (int p = 0; p < 3; p++)
#pragma unroll
    for (int q = 0; q < 3; q++){
      int yy = y + p - 1, xx = x + q - 1;
      float val = 0.f;
      if ((unsigned)yy < 48u && (unsigned)xx < 48u) val = fp[yy * 192 + xx * 2];
      uint16_t hi = f2b(val);
      uint16_t lo = f2b(val - b2f(hi));
      int t = p * 3 + q;
      xr[c * 9 + t] = hi;
      xr[576 + c * 9 + t] = lo;
      xr[1152 + c * 9 + t] = hi;
    }
}

// ---------------- correlation GEMM: Y[o][s], M=N=2304, K=1728 ----------------

__launch_bounds__(256)
__global__ void k_gemm_corr(const uint16_t* __restrict__ A, const uint16_t* __restrict__ B,
                            float* __restrict__ Cd){
  __shared__ __align__(16) uint16_t As[128 * 32];
  __shared__ __align__(16) uint16_t Bs[128 * 32];
  int item = blockIdx.z;
  int n0 = blockIdx.x * 128, m0 = blockIdx.y * 128;
  const uint16_t* Ap = A + (size_t)item * 2304 * 1728;
  const uint16_t* Bp = B + (size_t)item * 2304 * 1728;
  int tid = threadIdx.x;
  int wave = tid >> 6, lane = tid & 63, lm = lane & 15, lg = lane >> 4;
  int wy = wave >> 1, wx = wave & 1;
  f32x4 acc[4][4] = {};
  for (int kt = 0; kt < 54; kt++){
    int kb = kt * 32;
#pragma unroll
    for (int c = tid; c < 1024; c += 256){
      int cc = c & 511;
      int row = cc >> 2, col = (cc & 3) * 8;
      if (c < 512)
        gl_lds16(&Ap[(size_t)(m0 + row) * 1728 + kb + col], &As[cc * 8]);
      else
        gl_lds16(&Bp[(size_t)(n0 + row) * 1728 + kb + col], &Bs[cc * 8]);
    }
    __syncthreads();
    short8 af[4], bf[4];
#pragma unroll
    for (int i = 0; i < 4; i++){
      af[i] = *(const short8*)&As[(wy * 64 + i * 16 + lm) * 32 + lg * 8];
      bf[i] = *(const short8*)&Bs[(wx * 64 + i * 16 + lm) * 32 + lg * 8];
    }
#pragma unroll
    for (int i = 0; i < 4; i++)
#pragma unroll
      for (int j = 0; j < 4; j++)
        acc[i][j] = __builtin_amdgcn_mfma_f32_16x16x32_bf16(af[i], bf[j], acc[i][j], 0, 0, 0);
    __syncthreads();
  }
  float* Cp = Cd + (size_t)item * 2304 * 2304;
#pragma unroll
  for (int i = 0; i < 4; i++){
    int rb = m0 + wy * 64 + i * 16 + lg * 4;
#pragma unroll
    for (int j = 0; j < 4; j++){
      int cc = n0 + wx * 64 + j * 16 + lm;
#pragma unroll
      for (int r = 0; r < 4; r++)
        Cp[(size_t)(rb + r) * 2304 + cc] = acc[i][j][r];
    }
  }
}

// ---------------- merged fuse1 + fuse2p + transpose ----------------
// S[o][s] = sum_{d=-1..1} [g(o,d),g(s,d) valid] sum_{e=-1..1} [bounds] Y[g(o,d)+e][g(s,d)+e]
// writes St[s][o] (transposed) via LDS tile.

__global__ void k_fuse(const float* __restrict__ Y, float* __restrict__ St){
  __shared__ float tile[32][33];
  int item = blockIdx.z;
  int o0 = blockIdx.x * 32, s0 = blockIdx.y * 32;
  const float* ip = Y + (size_t)item * 2304 * 2304;
  float* op = St + (size_t)item * 2304 * 2304;
  int tx = threadIdx.x, ty = threadIdx.y;   // 32 x 8
  int s = s0 + tx;
  int cs[3]; cs[0] = gfun(s, -1); cs[1] = s; cs[2] = gfun(s, 1);
  for (int oy = ty; oy < 32; oy += 8){
    int o = o0 + oy;
    float acc = 0.f;
#pragma unroll
    for (int d = 0; d < 3; d++){
      int ro = gfun(o, d - 1);
      int cc = cs[d];
      if (ro < 0 || cc < 0) continue;
#pragma unroll
      for (int e = -1; e <= 1; e++){
        int a = ro + e, bb = cc + e;
        if ((unsigned)a < 2304u && (unsigned)bb < 2304u)
          acc += ip[(size_t)a * 2304 + bb];
      }
    }
    tile[oy][tx] = acc;
  }
  __syncthreads();
  for (int r = ty; r < 32; r += 8)
    op[(size_t)(s0 + r) * 2304 + o0 + tx] = tile[tx][r];
}

__global__ void k_softmax(const float* __restrict__ st, uint16_t* __restrict__ pt2){
  __shared__ float red[4];
  int s = blockIdx.x, item = blockIdx.y, t = threadIdx.x;
  const float* row = st + ((size_t)item * 2304 + s) * 2304;
  float v[9]; float mx = -3.4e38f;
#pragma unroll
  for (int u = 0; u < 9; u++){ v[u] = row[t + u * 256]; mx = fmaxf(mx, v[u]); }
#pragma unroll
  for (int off = 32; off > 0; off >>= 1) mx = fmaxf(mx, __shfl_xor(mx, off, 64));
  if ((t & 63) == 0) red[t >> 6] = mx;
  __syncthreads();
  mx = fmaxf(fmaxf(red[0], red[1]), fmaxf(red[2], red[3]));
  float sum = 0.f;
#pragma unroll
  for (int u = 0; u < 9; u++){ v[u] = __expf(10.f * (v[u] - mx)); sum += v[u]; }
#pragma unroll
  for (int off = 32; off > 0; off >>= 1) sum += __shfl_xor(sum, off, 64);
  __syncthreads();
  if ((t & 63) == 0) red[t >> 6] = sum;
  __syncthreads();
  float inv = 1.f / (red[0] + red[1] + red[2] + red[3]);
  uint16_t* pr = pt2 + ((size_t)item * 2500 + (size_t)(s / 48 + 1) * 50 + (s % 48) + 1) * 2304;
#pragma unroll
  for (int u = 0; u < 9; u++) pr[t + u * 256] = f2b(v[u] * inv);
}

// ---------------- raw 4x4 patch bank, layout [item][tap16][co][l] ----------------

__global__ void k_build_rwa(const float* __restrict__ bsrc, uint16_t* __restrict__ rwa){
  __shared__ uint16_t tile[64][66];
  int item = blockIdx.y, l0 = blockIdx.x * 64;
  const float* bp = bsrc + (size_t)item * 64 * 9216;
  int wave = threadIdx.x >> 6, lane = threadIdx.x & 63;
  for (int tap = 0; tap < 16; tap++){
    int py = tap >> 2, qx = tap & 3;
#pragma unroll
    for (int step = 0; step < 16; step++){
      int lsub = wave * 16 + step;
      int l = l0 + lsub, co = lane;
      int m = l * 64 + co;
      int c0 = m / 2304, rem = m % 2304, i = rem / 48, jj = rem % 48;
      int Y = 2 * i + py - 1, X = 2 * jj + qx - 1;
      float val = 0.f;
      if ((unsigned)Y < 96u && (unsigned)X < 96u) val = bp[(size_t)c0 * 9216 + Y * 96 + X];
      tile[lsub][co] = f2b(val);
    }
    __syncthreads();
#pragma unroll
    for (int step = 0; step < 16; step++){
      int co = wave * 16 + step;
      rwa[(((size_t)item * 16 + tap) * 64 + co) * 2304 + l0 + lane] = tile[lane][co];
    }
    __syncthreads();
  }
}

// ---------------- deconv: split-K over ay tap-half, fp32 partials ----------------

__launch_bounds__(256)
__global__ void k_deconv(const uint16_t* __restrict__ rwa, const uint16_t* __restrict__ pt2,
                         float* __restrict__ part){
  __shared__ __align__(16) uint16_t As[64 * 32];
  __shared__ __align__(16) uint16_t Bs[128 * 32];
  int n0 = blockIdx.x * 128, th = blockIdx.y, z = blockIdx.z;
  int item = z >> 2, phase = z & 3;
  int fy = phase >> 1, fx = phase & 1;
  int ay = th;
  int tid = threadIdx.x, wave = tid >> 6, lane = tid & 63, lm = lane & 15, lg = lane >> 4;
  const uint16_t* Pp = pt2 + (size_t)item * 2500 * 2304;
  const uint16_t* Rp = rwa + (size_t)item * 16 * 64 * 2304;
  f32x4 acc[4][2] = {};
  for (int ax = 0; ax < 2; ax++){
    int py = 3 - fy - 2 * ay, qx = 3 - fx - 2 * ax;
    const uint16_t* Ap = Rp + (size_t)(py * 4 + qx) * 64 * 2304;
    for (int kt = 0; kt < 72; kt++){
      int kb = kt * 32;
#pragma unroll
      for (int c = tid; c < 768; c += 256){
        if (c < 256){
          int row = c >> 2, col = (c & 3) * 8;
          gl_lds16(&Ap[(size_t)row * 2304 + kb + col], &As[c * 8]);
        } else {
          int cc = c - 256; int row = cc >> 2, col = (cc & 3) * 8;
          int n = n0 + row; int my = n / 48, mx = n % 48;
          int prow = (my + ay + fy) * 50 + (mx + ax + fx);
          gl_lds16(&Pp[(size_t)prow * 2304 + kb + col], &Bs[cc * 8]);
        }
      }
      __syncthreads();
      short8 af[4], bf[2];
#pragma unroll
      for (int i = 0; i < 4; i++) af[i] = *(const short8*)&As[(i * 16 + lm) * 32 + lg * 8];
#pragma unroll
      for (int j = 0; j < 2; j++) bf[j] = *(const short8*)&Bs[(wave * 32 + j * 16 + lm) * 32 + lg * 8];
#pragma unroll
      for (int i = 0; i < 4; i++)
#pragma unroll
        for (int j = 0; j < 2; j++)
          acc[i][j] = __builtin_amdgcn_mfma_f32_16x16x32_bf16(af[i], bf[j], acc[i][j], 0, 0, 0);
      __syncthreads();
    }
  }
  float* pp = part + ((size_t)(th * 16 + z) * 64) * 2304;
#pragma unroll
  for (int i = 0; i < 4; i++)
#pragma unroll
    for (int j = 0; j < 2; j++){
      int n = n0 + wave * 32 + j * 16 + lm;
#pragma unroll
      for (int r = 0; r < 4; r++){
        int co = i * 16 + lg * 4 + r;
        pp[(size_t)co * 2304 + n] = acc[i][j][r];
      }
    }
}

__global__ void k_dred(const float* __restrict__ part, uint16_t* __restrict__ yb){
  int t = threadIdx.x;
  int n = blockIdx.x * 256 + t;
  int co = blockIdx.y, z = blockIdx.z;
  int item = z >> 2, phase = z & 3;
  int fy = phase >> 1, fx = phase & 1;
  size_t idx = ((size_t)z * 64 + co) * 2304 + n;
  float v = (part[idx] + part[(size_t)16 * 64 * 2304 + idx]) * 0.25f;
  int my = n / 48, mx = n % 48;
  yb[((size_t)item * 64 + co) * 9216 + (2 * my + fy) * 96 + 2 * mx + fx] = f2b(v);
}

// ---------------- final 3x3 convs ----------------

__global__ void k_pack_w(const float* __restrict__ w1, const float* __restrict__ w2,
                         uint16_t* __restrict__ p1, uint16_t* __restrict__ p2){
  int i = blockIdx.x * 256 + threadIdx.x;
  if (i < 36864){ p1[i] = f2b(w1[i]); p2[i] = f2b(w2[i]); }
}

__global__ void k_im2col(const uint16_t* __restrict__ src, uint16_t* __restrict__ dst){
  int pix = blockIdx.x, item = blockIdx.y, ci = threadIdx.x;
  int y = pix / 96, x = pix % 96;
  const uint16_t* sp = src + ((size_t)item * 64 + ci) * 9216;
  uint16_t* dr = dst + ((size_t)item * 9216 + pix) * 576 + ci * 9;
#pragma unroll
  for (int p = 0; p < 3; p++)
#pragma unroll
    for (int q = 0; q < 3; q++){
      int yy = y + p - 1, xx = x + q - 1;
      dr[p * 3 + q] = ((unsigned)yy < 96u && (unsigned)xx < 96u) ? sp[yy * 96 + xx] : (uint16_t)0;
    }
}

__launch_bounds__(256)
__global__ void k_conv_gemm(const uint16_t* __restrict__ A, const uint16_t* __restrict__ B,
                            const float* __restrict__ bias,
                            uint16_t* __restrict__ dst16, float* __restrict__ dst32){
  __shared__ __align__(16) uint16_t As[64 * 32];
  __shared__ __align__(16) uint16_t Bs[128 * 32];
  int n0 = blockIdx.x * 128, item = blockIdx.z;
  int tid = threadIdx.x, wave = tid >> 6, lane = tid & 63, lm = lane & 15, lg = lane >> 4;
  const uint16_t* Bp = B + (size_t)item * 9216 * 576;
  f32x4 acc[4][2] = {};
  for (int kt = 0; kt < 18; kt++){
    int kb = kt * 32;
#pragma unroll
    for (int c = tid; c < 768; c += 256){
      if (c < 256){
        int row = c >> 2, col = (c & 3) * 8;
        gl_lds16(&A[(size_t)row * 576 + kb + col], &As[c * 8]);
      } else {
        int cc = c - 256; int row = cc >> 2, col = (cc & 3) * 8;
        gl_lds16(&Bp[(size_t)(n0 + row) * 576 + kb + col], &Bs[cc * 8]);
      }
    }
    __syncthreads();
    short8 af[4], bf[2];
#pragma unroll
    for (int i = 0; i < 4; i++) af[i] = *(const short8*)&As[(i * 16 + lm) * 32 + lg * 8];
#pragma unroll
    for (int j = 0; j < 2; j++) bf[j] = *(const short8*)&Bs[(wave * 32 + j * 16 + lm) * 32 + lg * 8];
#pragma unroll
    for (int i = 0; i < 4; i++)
#pragma unroll
      for (int j = 0; j < 2; j++)
        acc[i][j] = __builtin_amdgcn_mfma_f32_16x16x32_bf16(af[i], bf[j], acc[i][j], 0, 0, 0);
    __syncthreads();
  }
#pragma unroll
  for (int i = 0; i < 4; i++)
#pragma unroll
    for (int j = 0; j < 2; j++){
      int n = n0 + wave * 32 + j * 16 + lm;
#pragma unroll
      for (int r = 0; r < 4; r++){
        int co = i * 16 + lg * 4 + r;
        float val = acc[i][j][r] + bias[co];
        if (dst32) dst32[((size_t)item * 64 + co) * 9216 + n] = val;
        else       dst16[((size_t)item * 64 + co) * 9216 + n] = f2b(val);
      }
    }
}

// ---------------- launch ----------------

extern "C" void kernel_launch(void* const* d_in, const int* in_sizes, int n_in,
                              void* d_out, int out_size, void* d_ws, size_t ws_size,
                              hipStream_t stream){
  const float* f  = (const float*)d_in[0];
  const float* b  = (const float*)d_in[1];
  const float* w1 = (const float*)d_in[2];
  const float* b1 = (const float*)d_in[3];
  const float* w2 = (const float*)d_in[4];
  const float* b2 = (const float*)d_in[5];
  char* ws = (char*)d_ws;
  float*    Buf1 = (float*)ws;
  float*    Buf2 = (float*)(ws + SZ_BUF);
  uint16_t* Wn   = (uint16_t*)(ws + SZ_BUF);
  uint16_t* Xb   = Wn + (size_t)4 * 2304 * 1728;
  uint16_t* Pt2  = (uint16_t*)ws;                      // 46,080,000 B
  uint16_t* Rwa  = (uint16_t*)(ws + 46080000ull);      // 18,874,368 B
  uint16_t* Yb   = (uint16_t*)(ws + 64954368ull);      //  4,718,592 B
  uint16_t* Y1   = (uint16_t*)(ws + 69672960ull);      //  4,718,592 B
  uint16_t* Wp1  = (uint16_t*)(ws + 74391552ull);      //     73,728 B
  uint16_t* Wp2  = (uint16_t*)(ws + 74465280ull);      //     73,728 B
  float*    Part = (float*)(ws + SZ_BUF);              // 75,497,472 B (over Buf2)
  uint16_t* X2   = (uint16_t*)(ws + SZ_BUF);           // 42,467,328 B (over Part)
  float*    out  = (float*)d_out;

  k_build_wn<<<dim3(2304, 4), 64, 0, stream>>>(b, Wn);
  k_build_x<<<dim3(2304, 4), 64, 0, stream>>>(f, Xb);
  k_gemm_corr<<<dim3(18, 18, 4), 256, 0, stream>>>(Wn, Xb, Buf1);
  k_fuse<<<dim3(72, 72, 4), dim3(32, 8), 0, stream>>>(Buf1, Buf2);
  hipMemsetAsync(Pt2, 0, (size_t)4 * 2500 * 2304 * 2, stream);
  k_build_rwa<<<dim3(36, 4), 256, 0, stream>>>(b, Rwa);
  k_softmax<<<dim3(2304, 4), 256, 0, stream>>>(Buf2, Pt2);
  k_deconv<<<dim3(18, 2, 16), 256, 0, stream>>>(Rwa, Pt2, Part);
  k_dred<<<dim3(9, 64, 16), 256, 0, stream>>>(Part, Yb);
  k_pack_w<<<dim3(144), 256, 0, stream>>>(w1, w2, Wp1, Wp2);
  k_im2col<<<dim3(9216, 4), 64, 0, stream>>>(Yb, X2);
  k_conv_gemm<<<dim3(72, 1, 4), 256, 0, stream>>>(Wp1, X2, b1, Y1, nullptr);
  k_im2col<<<dim3(9216, 4), 64, 0, stream>>>(Y1, X2);
  k_conv_gemm<<<dim3(72, 1, 4), 256, 0, stream>>>(Wp2, X2, b2, nullptr, out);
}

// Round 4
// 769.955 us; speedup vs baseline: 1.3608x; 1.0528x over previous
//
#include <hip/hip_runtime.h>
#include <stdint.h>

// ContextualAttention on MI355X. Inputs/outputs float32; internals split-bf16 MFMA
// for correlation logits, plain bf16 MFMA elsewhere, fp32 fuse/softmax.
//
// Round 4 changes:
//  - gemm_corr now writes Yt[s][o] (A/B swapped; split-bf16 algebra symmetric)
//  - k_fuse + k_softmax merged into k_fuse_sm reading Yt with uniform-row/contig-col
//    9-gather (no St materialization)
//  - deconv split-K 4-way over (ay,ax), bf16 partials, grid(18,4,16)
//
// ws layout (bytes), total 169,869,312:
//  region A [0, 84934656):
//    phase1: Yt f32 (85 MB, corr logits transposed)
//    phase2: Part bf16 4x18,874,368 = [0, 75497472) | Yb [75497472, 80216064)
//            | Wp1 [80216064, +73728) | Wp2 [80289792, +73728)
//  region B [84934656, 169869312):
//    phase1: Wn (31850496) + Xb (31850496)
//    phase2: Pt2 bf16 [SZ_BUF, +46080000) | Rwa [SZ_BUF+46080000, +18874368)
//    phase3: X2 [SZ_BUF, +42467328) | Y1 [SZ_BUF+42467328, +4718592)

#define SZ_BUF 84934656ull
typedef __attribute__((ext_vector_type(8))) short short8;
typedef __attribute__((ext_vector_type(4))) float f32x4;

#if defined(__has_builtin)
#if __has_builtin(__builtin_amdgcn_global_load_lds)
#define HAVE_GLL 1
#endif
#endif

#ifdef HAVE_GLL
typedef const __attribute__((address_space(1))) void* gp1_t;
typedef __attribute__((address_space(3))) void* lp3_t;
__device__ __forceinline__ void gl_lds16(const void* g, void* l){
  __builtin_amdgcn_global_load_lds((gp1_t)g, (lp3_t)l, 16, 0, 0);
}
#else
__device__ __forceinline__ void gl_lds16(const void* g, void* l){
  *(short8*)l = *(const short8*)g;
}
#endif

__device__ __forceinline__ float b2f(uint16_t u){
  union { uint32_t i; float f; } v; v.i = ((uint32_t)u) << 16; return v.f;
}
__device__ __forceinline__ uint16_t f2b(float f){
  uint32_t x = __float_as_uint(f);
  uint32_t r = (x + 0x7FFFu + ((x >> 16) & 1u)) >> 16;
  return (uint16_t)r;
}
__device__ __forceinline__ int gfun(int x, int d){
  int t = (x % 48) * 48 + (x / 48) + d;
  if ((unsigned)t >= 2304u) return -1;
  return (t % 48) * 48 + (t / 48);
}

// ---------------- prep kernels ----------------

__global__ void k_build_wn(const float* __restrict__ bsrc, uint16_t* __restrict__ wn){
  int o = blockIdx.x, item = blockIdx.y, c = threadIdx.x;
  int m = o * 64 + c;
  int c0 = m / 2304, rem = m % 2304, i = rem / 48, j = rem % 48;
  const float* bp = bsrc + ((size_t)item * 64 + c0) * 9216;
  float v[9]; float ss = 0.f;
#pragma unroll
  for (int p = 0; p < 3; p++)
#pragma unroll
    for (int q = 0; q < 3; q++){
      int y = i + p - 1, x = j + q - 1;
      float val = 0.f;
      if ((unsigned)y < 48u && (unsigned)x < 48u) val = bp[y * 192 + x * 2];
      v[p * 3 + q] = val; ss += val * val;
    }
#pragma unroll
  for (int off = 32; off > 0; off >>= 1) ss += __shfl_xor(ss, off, 64);
  float inv = 1.f / fmaxf(sqrtf(ss), 1e-4f);
  uint16_t* wr = wn + ((size_t)item * 2304 + o) * 1728;
#pragma unroll
  for (int t = 0; t < 9; t++){
    float fv = v[t] * inv;
    uint16_t hi = f2b(fv);
    uint16_t lo = f2b(fv - b2f(hi));
    wr[c * 9 + t] = hi;            // block 0: w_hi (x x_hi)
    wr[576 + c * 9 + t] = hi;      // block 1: w_hi (x x_lo)
    wr[1152 + c * 9 + t] = lo;     // block 2: w_lo (x x_hi)
  }
}

__global__ void k_build_x(const float* __restrict__ fsrc, uint16_t* __restrict__ xb){
  int s = blockIdx.x, item = blockIdx.y, c = threadIdx.x;
  int y = s / 48, x = s % 48;
  const float* fp = fsrc + ((size_t)item * 64 + c) * 9216;
  uint16_t* xr = xb + ((size_t)item * 2304 + s) * 1728;
#pragma unroll
  for (int p = 0; p < 3; p++)
#pragma unroll
    for (int q = 0; q < 3; q++){
      int yy = y + p - 1, xx = x + q - 1;
      float val = 0.f;
      if ((unsigned)yy < 48u && (unsigned)xx < 48u) val = fp[yy * 192 + xx * 2];
      uint16_t hi = f2b(val);
      uint16_t lo = f2b(val - b2f(hi));
      int t = p * 3 + q;
      xr[c * 9 + t] = hi;
      xr[576 + c * 9 + t] = lo;
      xr[1152 + c * 9 + t] = hi;
    }
}

// ---------------- correlation GEMM: Yt[s][o] = X @ Wn^T, M=N=2304, K=1728 ----------------

__launch_bounds__(256)
__global__ void k_gemm_corr(const uint16_t* __restrict__ A, const uint16_t* __restrict__ B,
                            float* __restrict__ Cd){
  __shared__ __align__(16) uint16_t As[128 * 32];
  __shared__ __align__(16) uint16_t Bs[128 * 32];
  int item = blockIdx.z;
  int n0 = blockIdx.x * 128, m0 = blockIdx.y * 128;
  const uint16_t* Ap = A + (size_t)item * 2304 * 1728;
  const uint16_t* Bp = B + (size_t)item * 2304 * 1728;
  int tid = threadIdx.x;
  int wave = tid >> 6, lane = tid & 63, lm = lane & 15, lg = lane >> 4;
  int wy = wave >> 1, wx = wave & 1;
  f32x4 acc[4][4] = {};
  for (int kt = 0; kt < 54; kt++){
    int kb = kt * 32;
#pragma unroll
    for (int c = tid; c < 1024; c += 256){
      int cc = c & 511;
      int row = cc >> 2, col = (cc & 3) * 8;
      if (c < 512)
        gl_lds16(&Ap[(size_t)(m0 + row) * 1728 + kb + col], &As[cc * 8]);
      else
        gl_lds16(&Bp[(size_t)(n0 + row) * 1728 + kb + col], &Bs[cc * 8]);
    }
    __syncthreads();
    short8 af[4], bf[4];
#pragma unroll
    for (int i = 0; i < 4; i++){
      af[i] = *(const short8*)&As[(wy * 64 + i * 16 + lm) * 32 + lg * 8];
      bf[i] = *(const short8*)&Bs[(wx * 64 + i * 16 + lm) * 32 + lg * 8];
    }
#pragma unroll
    for (int i = 0; i < 4; i++)
#pragma unroll
      for (int j = 0; j < 4; j++)
        acc[i][j] = __builtin_amdgcn_mfma_f32_16x16x32_bf16(af[i], bf[j], acc[i][j], 0, 0, 0);
    __syncthreads();
  }
  float* Cp = Cd + (size_t)item * 2304 * 2304;
#pragma unroll
  for (int i = 0; i < 4; i++){
    int rb = m0 + wy * 64 + i * 16 + lg * 4;
#pragma unroll
    for (int j = 0; j < 4; j++){
      int cc = n0 + wx * 64 + j * 16 + lm;
#pragma unroll
      for (int r = 0; r < 4; r++)
        Cp[(size_t)(rb + r) * 2304 + cc] = acc[i][j][r];
    }
  }
}

// ---------------- merged fuse + softmax ----------------
// St[s][o] = sum_{d} [g(s,d),g(o,d) valid] sum_{e} [bounds] Yt[g(s,d)+e][g(o,d)+e]
// then softmax over o (scale 10), write padded Pt2 row (bf16).

__global__ void k_fuse_sm(const float* __restrict__ Yt, uint16_t* __restrict__ pt2){
  __shared__ float red[4];
  int s = blockIdx.x, item = blockIdx.y, t = threadIdx.x;
  const float* yp = Yt + (size_t)item * 2304 * 2304;
  int rs[3]; rs[0] = gfun(s, -1); rs[1] = s; rs[2] = gfun(s, 1);
  float v[9];
#pragma unroll
  for (int u = 0; u < 9; u++){
    int o = t + u * 256;
    int go[3]; go[0] = gfun(o, -1); go[1] = o; go[2] = gfun(o, 1);
    float acc = 0.f;
#pragma unroll
    for (int d = 0; d < 3; d++){
      int a0 = rs[d], b0 = go[d];
      if (a0 < 0 || b0 < 0) continue;
#pragma unroll
      for (int e = -1; e <= 1; e++){
        int a = a0 + e, bb = b0 + e;
        if ((unsigned)a < 2304u && (unsigned)bb < 2304u)
          acc += yp[(size_t)a * 2304 + bb];
      }
    }
    v[u] = acc;
  }
  float mx = -3.4e38f;
#pragma unroll
  for (int u = 0; u < 9; u++) mx = fmaxf(mx, v[u]);
#pragma unroll
  for (int off = 32; off > 0; off >>= 1) mx = fmaxf(mx, __shfl_xor(mx, off, 64));
  if ((t & 63) == 0) red[t >> 6] = mx;
  __syncthreads();
  mx = fmaxf(fmaxf(red[0], red[1]), fmaxf(red[2], red[3]));
  float sum = 0.f;
#pragma unroll
  for (int u = 0; u < 9; u++){ v[u] = __expf(10.f * (v[u] - mx)); sum += v[u]; }
#pragma unroll
  for (int off = 32; off > 0; off >>= 1) sum += __shfl_xor(sum, off, 64);
  __syncthreads();
  if ((t & 63) == 0) red[t >> 6] = sum;
  __syncthreads();
  float inv = 1.f / (red[0] + red[1] + red[2] + red[3]);
  uint16_t* pr = pt2 + ((size_t)item * 2500 + (size_t)(s / 48 + 1) * 50 + (s % 48) + 1) * 2304;
#pragma unroll
  for (int u = 0; u < 9; u++) pr[t + u * 256] = f2b(v[u] * inv);
}

// ---------------- raw 4x4 patch bank, layout [item][tap16][co][l] ----------------

__global__ void k_build_rwa(const float* __restrict__ bsrc, uint16_t* __restrict__ rwa){
  __shared__ uint16_t tile[64][66];
  int item = blockIdx.y, l0 = blockIdx.x * 64;
  const float* bp = bsrc + (size_t)item * 64 * 9216;
  int wave = threadIdx.x >> 6, lane = threadIdx.x & 63;
  for (int tap = 0; tap < 16; tap++){
    int py = tap >> 2, qx = tap & 3;
#pragma unroll
    for (int step = 0; step < 16; step++){
      int lsub = wave * 16 + step;
      int l = l0 + lsub, co = lane;
      int m = l * 64 + co;
      int c0 = m / 2304, rem = m % 2304, i = rem / 48, jj = rem % 48;
      int Y = 2 * i + py - 1, X = 2 * jj + qx - 1;
      float val = 0.f;
      if ((unsigned)Y < 96u && (unsigned)X < 96u) val = bp[(size_t)c0 * 9216 + Y * 96 + X];
      tile[lsub][co] = f2b(val);
    }
    __syncthreads();
#pragma unroll
    for (int step = 0; step < 16; step++){
      int co = wave * 16 + step;
      rwa[(((size_t)item * 16 + tap) * 64 + co) * 2304 + l0 + lane] = tile[lane][co];
    }
    __syncthreads();
  }
}

// ---------------- deconv: split-K 4-way over (ay,ax), bf16 partials ----------------

__launch_bounds__(256)
__global__ void k_deconv(const uint16_t* __restrict__ rwa, const uint16_t* __restrict__ pt2,
                         uint16_t* __restrict__ part){
  __shared__ __align__(16) uint16_t As[64 * 32];
  __shared__ __align__(16) uint16_t Bs[128 * 32];
  int n0 = blockIdx.x * 128, th = blockIdx.y, z = blockIdx.z;
  int item = z >> 2, phase = z & 3;
  int fy = phase >> 1, fx = phase & 1;
  int ay = th >> 1, ax = th & 1;
  int tid = threadIdx.x, wave = tid >> 6, lane = tid & 63, lm = lane & 15, lg = lane >> 4;
  const uint16_t* Pp = pt2 + (size_t)item * 2500 * 2304;
  int py = 3 - fy - 2 * ay, qx = 3 - fx - 2 * ax;
  const uint16_t* Ap = rwa + ((size_t)item * 16 + py * 4 + qx) * 64 * 2304;
  f32x4 acc[4][2] = {};
  for (int kt = 0; kt < 72; kt++){
    int kb = kt * 32;
#pragma unroll
    for (int c = tid; c < 768; c += 256){
      if (c < 256){
        int row = c >> 2, col = (c & 3) * 8;
        gl_lds16(&Ap[(size_t)row * 2304 + kb + col], &As[c * 8]);
      } else {
        int cc = c - 256; int row = cc >> 2, col = (cc & 3) * 8;
        int n = n0 + row; int my = n / 48, mx = n % 48;
        int prow = (my + ay + fy) * 50 + (mx + ax + fx);
        gl_lds16(&Pp[(size_t)prow * 2304 + kb + col], &Bs[cc * 8]);
      }
    }
    __syncthreads();
    short8 af[4], bf[2];
#pragma unroll
    for (int i = 0; i < 4; i++) af[i] = *(const short8*)&As[(i * 16 + lm) * 32 + lg * 8];
#pragma unroll
    for (int j = 0; j < 2; j++) bf[j] = *(const short8*)&Bs[(wave * 32 + j * 16 + lm) * 32 + lg * 8];
#pragma unroll
    for (int i = 0; i < 4; i++)
#pragma unroll
      for (int j = 0; j < 2; j++)
        acc[i][j] = __builtin_amdgcn_mfma_f32_16x16x32_bf16(af[i], bf[j], acc[i][j], 0, 0, 0);
    __syncthreads();
  }
  uint16_t* pp = part + ((size_t)(th * 16 + z) * 64) * 2304;
#pragma unroll
  for (int i = 0; i < 4; i++)
#pragma unroll
    for (int j = 0; j < 2; j++){
      int n = n0 + wave * 32 + j * 16 + lm;
#pragma unroll
      for (int r = 0; r < 4; r++){
        int co = i * 16 + lg * 4 + r;
        pp[(size_t)co * 2304 + n] = f2b(acc[i][j][r]);
      }
    }
}

__global__ void k_dred(const uint16_t* __restrict__ part, uint16_t* __restrict__ yb){
  int t = threadIdx.x;
  int n = blockIdx.x * 256 + t;
  int co = blockIdx.y, z = blockIdx.z;
  int item = z >> 2, phase = z & 3;
  int fy = phase >> 1, fx = phase & 1;
  size_t idx = ((size_t)z * 64 + co) * 2304 + n;
  const size_t stride = (size_t)16 * 64 * 2304;
  float v = (b2f(part[idx]) + b2f(part[stride + idx]) +
             b2f(part[2 * stride + idx]) + b2f(part[3 * stride + idx])) * 0.25f;
  int my = n / 48, mx = n % 48;
  yb[((size_t)item * 64 + co) * 9216 + (2 * my + fy) * 96 + 2 * mx + fx] = f2b(v);
}

// ---------------- final 3x3 convs ----------------

__global__ void k_pack_w(const float* __restrict__ w1, const float* __restrict__ w2,
                         uint16_t* __restrict__ p1, uint16_t* __restrict__ p2){
  int i = blockIdx.x * 256 + threadIdx.x;
  if (i < 36864){ p1[i] = f2b(w1[i]); p2[i] = f2b(w2[i]); }
}

__global__ void k_im2col(const uint16_t* __restrict__ src, uint16_t* __restrict__ dst){
  int pix = blockIdx.x, item = blockIdx.y, ci = threadIdx.x;
  int y = pix / 96, x = pix % 96;
  const uint16_t* sp = src + ((size_t)item * 64 + ci) * 9216;
  uint16_t* dr = dst + ((size_t)item * 9216 + pix) * 576 + ci * 9;
#pragma unroll
  for (int p = 0; p < 3; p++)
#pragma unroll
    for (int q = 0; q < 3; q++){
      int yy = y + p - 1, xx = x + q - 1;
      dr[p * 3 + q] = ((unsigned)yy < 96u && (unsigned)xx < 96u) ? sp[yy * 96 + xx] : (uint16_t)0;
    }
}

__launch_bounds__(256)
__global__ void k_conv_gemm(const uint16_t* __restrict__ A, const uint16_t* __restrict__ B,
                            const float* __restrict__ bias,
                            uint16_t* __restrict__ dst16, float* __restrict__ dst32){
  __shared__ __align__(16) uint16_t As[64 * 32];
  __shared__ __align__(16) uint16_t Bs[128 * 32];
  int n0 = blockIdx.x * 128, item = blockIdx.z;
  int tid = threadIdx.x, wave = tid >> 6, lane = tid & 63, lm = lane & 15, lg = lane >> 4;
  const uint16_t* Bp = B + (size_t)item * 9216 * 576;
  f32x4 acc[4][2] = {};
  for (int kt = 0; kt < 18; kt++){
    int kb = kt * 32;
#pragma unroll
    for (int c = tid; c < 768; c += 256){
      if (c < 256){
        int row = c >> 2, col = (c & 3) * 8;
        gl_lds16(&A[(size_t)row * 576 + kb + col], &As[c * 8]);
      } else {
        int cc = c - 256; int row = cc >> 2, col = (cc & 3) * 8;
        gl_lds16(&Bp[(size_t)(n0 + row) * 576 + kb + col], &Bs[cc * 8]);
      }
    }
    __syncthreads();
    short8 af[4], bf[2];
#pragma unroll
    for (int i = 0; i < 4; i++) af[i] = *(const short8*)&As[(i * 16 + lm) * 32 + lg * 8];
#pragma unroll
    for (int j = 0; j < 2; j++) bf[j] = *(const short8*)&Bs[(wave * 32 + j * 16 + lm) * 32 + lg * 8];
#pragma unroll
    for (int i = 0; i < 4; i++)
#pragma unroll
      for (int j = 0; j < 2; j++)
        acc[i][j] = __builtin_amdgcn_mfma_f32_16x16x32_bf16(af[i], bf[j], acc[i][j], 0, 0, 0);
    __syncthreads();
  }
#pragma unroll
  for (int i = 0; i < 4; i++)
#pragma unroll
    for (int j = 0; j < 2; j++){
      int n = n0 + wave * 32 + j * 16 + lm;
#pragma unroll
      for (int r = 0; r < 4; r++){
        int co = i * 16 + lg * 4 + r;
        float val = acc[i][j][r] + bias[co];
        if (dst32) dst32[((size_t)item * 64 + co) * 9216 + n] = val;
        else       dst16[((size_t)item * 64 + co) * 9216 + n] = f2b(val);
      }
    }
}

// ---------------- launch ----------------

extern "C" void kernel_launch(void* const* d_in, const int* in_sizes, int n_in,
                              void* d_out, int out_size, void* d_ws, size_t ws_size,
                              hipStream_t stream){
  const float* f  = (const float*)d_in[0];
  const float* b  = (const float*)d_in[1];
  const float* w1 = (const float*)d_in[2];
  const float* b1 = (const float*)d_in[3];
  const float* w2 = (const float*)d_in[4];
  const float* b2 = (const float*)d_in[5];
  char* ws = (char*)d_ws;
  // region A
  float*    Yt   = (float*)ws;                          // 84,934,656 B
  uint16_t* Part = (uint16_t*)ws;                       // 75,497,472 B (over dead Yt)
  uint16_t* Yb   = (uint16_t*)(ws + 75497472ull);       //  4,718,592 B
  uint16_t* Wp1  = (uint16_t*)(ws + 80216064ull);       //     73,728 B
  uint16_t* Wp2  = (uint16_t*)(ws + 80289792ull);       //     73,728 B
  // region B
  uint16_t* Wn   = (uint16_t*)(ws + SZ_BUF);            // 31,850,496 B
  uint16_t* Xb   = Wn + (size_t)4 * 2304 * 1728;        // 31,850,496 B
  uint16_t* Pt2  = (uint16_t*)(ws + SZ_BUF);            // 46,080,000 B (over dead Wn/Xb)
  uint16_t* Rwa  = (uint16_t*)(ws + SZ_BUF + 46080000ull); // 18,874,368 B
  uint16_t* X2   = (uint16_t*)(ws + SZ_BUF);            // 42,467,328 B (over dead Pt2)
  uint16_t* Y1   = (uint16_t*)(ws + SZ_BUF + 42467328ull); // 4,718,592 B
  float*    out  = (float*)d_out;

  k_build_wn<<<dim3(2304, 4), 64, 0, stream>>>(b, Wn);
  k_build_x<<<dim3(2304, 4), 64, 0, stream>>>(f, Xb);
  k_gemm_corr<<<dim3(18, 18, 4), 256, 0, stream>>>(Xb, Wn, Yt);   // A=Xb -> rows=s
  hipMemsetAsync(Pt2, 0, (size_t)4 * 2500 * 2304 * 2, stream);    // Wn/Xb dead now
  k_build_rwa<<<dim3(36, 4), 256, 0, stream>>>(b, Rwa);
  k_fuse_sm<<<dim3(2304, 4), 256, 0, stream>>>(Yt, Pt2);
  k_deconv<<<dim3(18, 4, 16), 256, 0, stream>>>(Rwa, Pt2, Part);  // Yt dead now
  k_dred<<<dim3(9, 64, 16), 256, 0, stream>>>(Part, Yb);
  k_pack_w<<<dim3(144), 256, 0, stream>>>(w1, w2, Wp1, Wp2);
  k_im2col<<<dim3(9216, 4), 64, 0, stream>>>(Yb, X2);             // Pt2/Rwa dead now
  k_conv_gemm<<<dim3(72, 1, 4), 256, 0, stream>>>(Wp1, X2, b1, Y1, nullptr);
  k_im2col<<<dim3(9216, 4), 64, 0, stream>>>(Y1, X2);
  k_conv_gemm<<<dim3(72, 1, 4), 256, 0, stream>>>(Wp2, X2, b2, nullptr, out);
}

// Round 5
// 720.188 us; speedup vs baseline: 1.4548x; 1.0691x over previous
//
#include <hip/hip_runtime.h>
#include <stdint.h>

// ContextualAttention on MI355X. Inputs/outputs float32; internals split-bf16 MFMA
// for correlation logits, plain bf16 MFMA elsewhere, fp32 fuse/softmax.
//
// Round 5 changes:
//  - k_fuse_sm vectorized: float4 diagonal gathers (g(x,+-1)=x+-48 affine per 4-group,
//    scalar fallback only at 48-grid wrap rows)
//  - XOR swizzle (j ^= (row>>2)&3) of k-block slots in all MFMA LDS tiles: applied on
//    the per-lane GLOBAL src address so global_load_lds dest stays lane-contiguous;
//    8-way bank conflict -> 2-way (free)
//  - Pt2 memset replaced by k_zero_pad (196 pad rows/item only)
//
// ws layout (bytes), total 169,869,312:
//  region A [0, 84934656):
//    phase1: Yt f32 (85 MB); phase2: Part bf16 4x18,874,368 | Yb @75497472 | Wp1/Wp2
//  region B [84934656, ...): Wn+Xb -> Pt2+Rwa -> X2+Y1

#define SZ_BUF 84934656ull
typedef __attribute__((ext_vector_type(8))) short short8;
typedef __attribute__((ext_vector_type(4))) float f32x4;
typedef __attribute__((ext_vector_type(4), aligned(4))) float f32x4u;
typedef __attribute__((ext_vector_type(4))) short s16x4;

#if defined(__has_builtin)
#if __has_builtin(__builtin_amdgcn_global_load_lds)
#define HAVE_GLL 1
#endif
#endif

#ifdef HAVE_GLL
typedef const __attribute__((address_space(1))) void* gp1_t;
typedef __attribute__((address_space(3))) void* lp3_t;
__device__ __forceinline__ void gl_lds16(const void* g, void* l){
  __builtin_amdgcn_global_load_lds((gp1_t)g, (lp3_t)l, 16, 0, 0);
}
#else
__device__ __forceinline__ void gl_lds16(const void* g, void* l){
  *(short8*)l = *(const short8*)g;
}
#endif

__device__ __forceinline__ float b2f(uint16_t u){
  union { uint32_t i; float f; } v; v.i = ((uint32_t)u) << 16; return v.f;
}
__device__ __forceinline__ uint16_t f2b(float f){
  uint32_t x = __float_as_uint(f);
  uint32_t r = (x + 0x7FFFu + ((x >> 16) & 1u)) >> 16;
  return (uint16_t)r;
}
__device__ __forceinline__ int gfun(int x, int d){
  int t = (x % 48) * 48 + (x / 48) + d;
  if ((unsigned)t >= 2304u) return -1;
  return (t % 48) * 48 + (t / 48);
}

// ---------------- prep kernels ----------------

__global__ void k_build_wn(const float* __restrict__ bsrc, uint16_t* __restrict__ wn){
  int o = blockIdx.x, item = blockIdx.y, c = threadIdx.x;
  int m = o * 64 + c;
  int c0 = m / 2304, rem = m % 2304, i = rem / 48, j = rem % 48;
  const float* bp = bsrc + ((size_t)item * 64 + c0) * 9216;
  float v[9]; float ss = 0.f;
#pragma unroll
  for (int p = 0; p < 3; p++)
#pragma unroll
    for (int q = 0; q < 3; q++){
      int y = i + p - 1, x = j + q - 1;
      float val = 0.f;
      if ((unsigned)y < 48u && (unsigned)x < 48u) val = bp[y * 192 + x * 2];
      v[p * 3 + q] = val; ss += val * val;
    }
#pragma unroll
  for (int off = 32; off > 0; off >>= 1) ss += __shfl_xor(ss, off, 64);
  float inv = 1.f / fmaxf(sqrtf(ss), 1e-4f);
  uint16_t* wr = wn + ((size_t)item * 2304 + o) * 1728;
#pragma unroll
  for (int t = 0; t < 9; t++){
    float fv = v[t] * inv;
    uint16_t hi = f2b(fv);
    uint16_t lo = f2b(fv - b2f(hi));
    wr[c * 9 + t] = hi;            // block 0: w_hi (x x_hi)
    wr[576 + c * 9 + t] = hi;      // block 1: w_hi (x x_lo)
    wr[1152 + c * 9 + t] = lo;     // block 2: w_lo (x x_hi)
  }
}

__global__ void k_build_x(const float* __restrict__ fsrc, uint16_t* __restrict__ xb){
  int s = blockIdx.x, item = blockIdx.y, c = threadIdx.x;
  int y = s / 48, x = s % 48;
  const float* fp = fsrc + ((size_t)item * 64 + c) * 9216;
  uint16_t* xr = xb + ((size_t)item * 2304 + s) * 1728;
#pragma unroll
  for (int p = 0; p < 3; p++)
#pragma unroll
    for (int q = 0; q < 3; q++){
      int yy = y + p - 1, xx = x + q - 1;
      float val = 0.f;
      if ((unsigned)yy < 48u && (unsigned)xx < 48u) val = fp[yy * 192 + xx * 2];
      uint16_t hi = f2b(val);
      uint16_t lo = f2b(val - b2f(hi));
      int t = p * 3 + q;
      xr[c * 9 + t] = hi;
      xr[576 + c * 9 + t] = lo;
      xr[1152 + c * 9 + t] = hi;
    }
}

// ---------------- correlation GEMM: Yt[s][o] = X @ Wn^T, M=N=2304, K=1728 ----------------

__launch_bounds__(256)
__global__ void k_gemm_corr(const uint16_t* __restrict__ A, const uint16_t* __restrict__ B,
                            float* __restrict__ Cd){
  __shared__ __align__(16) uint16_t As[128 * 32];
  __shared__ __align__(16) uint16_t Bs[128 * 32];
  int item = blockIdx.z;
  int n0 = blockIdx.x * 128, m0 = blockIdx.y * 128;
  const uint16_t* Ap = A + (size_t)item * 2304 * 1728;
  const uint16_t* Bp = B + (size_t)item * 2304 * 1728;
  int tid = threadIdx.x;
  int wave = tid >> 6, lane = tid & 63, lm = lane & 15, lg = lane >> 4;
  int wy = wave >> 1, wx = wave & 1;
  int swl = (lg ^ ((lm >> 2) & 3)) * 8;
  f32x4 acc[4][4] = {};
  for (int kt = 0; kt < 54; kt++){
    int kb = kt * 32;
#pragma unroll
    for (int c = tid; c < 1024; c += 256){
      int cc = c & 511;
      int row = cc >> 2, j = cc & 3;
      int sw = (j ^ ((row >> 2) & 3)) * 8;
      if (c < 512)
        gl_lds16(&Ap[(size_t)(m0 + row) * 1728 + kb + sw], &As[cc * 8]);
      else
        gl_lds16(&Bp[(size_t)(n0 + row) * 1728 + kb + sw], &Bs[cc * 8]);
    }
    __syncthreads();
    short8 af[4], bf[4];
#pragma unroll
    for (int i = 0; i < 4; i++){
      af[i] = *(const short8*)&As[(wy * 64 + i * 16 + lm) * 32 + swl];
      bf[i] = *(const short8*)&Bs[(wx * 64 + i * 16 + lm) * 32 + swl];
    }
#pragma unroll
    for (int i = 0; i < 4; i++)
#pragma unroll
      for (int j = 0; j < 4; j++)
        acc[i][j] = __builtin_amdgcn_mfma_f32_16x16x32_bf16(af[i], bf[j], acc[i][j], 0, 0, 0);
    __syncthreads();
  }
  float* Cp = Cd + (size_t)item * 2304 * 2304;
#pragma unroll
  for (int i = 0; i < 4; i++){
    int rb = m0 + wy * 64 + i * 16 + lg * 4;
#pragma unroll
    for (int j = 0; j < 4; j++){
      int cc = n0 + wx * 64 + j * 16 + lm;
#pragma unroll
      for (int r = 0; r < 4; r++)
        Cp[(size_t)(rb + r) * 2304 + cc] = acc[i][j][r];
    }
  }
}

// ---------------- merged fuse + softmax (vectorized) ----------------
// St[s][o] = sum_{d,e} Yt[g(s,d)+e][g(o,d)+e]; g affine per 4-aligned o-group except
// 48-grid wrap rows. Softmax over o (scale 10) -> padded Pt2 row (bf16).

__global__ void k_fuse_sm(const float* __restrict__ Yt, uint16_t* __restrict__ pt2){
  __shared__ float red[4];
  int s = blockIdx.x, item = blockIdx.y, t = threadIdx.x;
  const float* yp = Yt + (size_t)item * 2304 * 2304;
  int rs[3]; rs[0] = gfun(s, -1); rs[1] = s; rs[2] = gfun(s, 1);
  int nact = (t < 64) ? 3 : 2;
  f32x4u v[3];
  for (int u = 0; u < 3; u++){
    f32x4u acc = {0.f, 0.f, 0.f, 0.f};
    if (u < nact){
      int g = t + u * 256;
      int o0 = 4 * g, orr = o0 / 48, oc0 = o0 % 48;
#pragma unroll
      for (int dd = 0; dd < 3; dd++){
        int a0 = rs[dd];
        if (a0 < 0) continue;
        int d = dd - 1;
        int base; int vm = 0xF;
        if (d == 0) base = o0;
        else {
          int tor = orr + d;
          if ((unsigned)tor < 48u) base = tor * 48 + oc0;
          else if (tor < 0){ base = 2255 + oc0; if (oc0 == 0) vm = 0xE; }
          else { base = oc0 + 1; if (oc0 == 44) vm = 0x7; }
        }
#pragma unroll
        for (int e = -1; e <= 1; e++){
          int a = a0 + e;
          if ((unsigned)a >= 2304u) continue;
          int cb = base + e;
          const float* rowp = yp + (size_t)a * 2304;
          if (vm == 0xF && cb >= 0 && cb + 3 < 2304){
            acc += *(const f32x4u*)&rowp[cb];
          } else {
#pragma unroll
            for (int i = 0; i < 4; i++)
              if ((vm >> i) & 1){
                int c2 = cb + i;
                if ((unsigned)c2 < 2304u) acc[i] += rowp[c2];
              }
          }
        }
      }
    }
    v[u] = acc;
  }
  float mx = -3.4e38f;
  for (int u = 0; u < nact; u++)
#pragma unroll
    for (int i = 0; i < 4; i++) mx = fmaxf(mx, v[u][i]);
#pragma unroll
  for (int off = 32; off > 0; off >>= 1) mx = fmaxf(mx, __shfl_xor(mx, off, 64));
  if ((t & 63) == 0) red[t >> 6] = mx;
  __syncthreads();
  mx = fmaxf(fmaxf(red[0], red[1]), fmaxf(red[2], red[3]));
  float sum = 0.f;
  for (int u = 0; u < nact; u++)
#pragma unroll
    for (int i = 0; i < 4; i++){ v[u][i] = __expf(10.f * (v[u][i] - mx)); sum += v[u][i]; }
#pragma unroll
  for (int off = 32; off > 0; off >>= 1) sum += __shfl_xor(sum, off, 64);
  __syncthreads();
  if ((t & 63) == 0) red[t >> 6] = sum;
  __syncthreads();
  float inv = 1.f / (red[0] + red[1] + red[2] + red[3]);
  uint16_t* pr = pt2 + ((size_t)item * 2500 + (size_t)(s / 48 + 1) * 50 + (s % 48) + 1) * 2304;
  for (int u = 0; u < nact; u++){
    s16x4 w;
#pragma unroll
    for (int i = 0; i < 4; i++) w[i] = (short)f2b(v[u][i] * inv);
    *(s16x4*)&pr[4 * (t + u * 256)] = w;
  }
}

__global__ void k_zero_pad(uint16_t* __restrict__ pt2){
  int p = blockIdx.x, item = blockIdx.y, t = threadIdx.x;
  int sy, sx;
  if (p < 50){ sy = 0; sx = p; }
  else if (p < 100){ sy = 49; sx = p - 50; }
  else if (p < 148){ sy = p - 99; sx = 0; }
  else { sy = p - 147; sx = 49; }
  uint16_t* pr = pt2 + ((size_t)item * 2500 + sy * 50 + sx) * 2304;
  short8 z = {};
  for (int c = t; c < 288; c += 256) *(short8*)&pr[c * 8] = z;
}

// ---------------- raw 4x4 patch bank, layout [item][tap16][co][l] ----------------

__global__ void k_build_rwa(const float* __restrict__ bsrc, uint16_t* __restrict__ rwa){
  __shared__ uint16_t tile[64][66];
  int item = blockIdx.y, l0 = blockIdx.x * 64;
  const float* bp = bsrc + (size_t)item * 64 * 9216;
  int wave = threadIdx.x >> 6, lane = threadIdx.x & 63;
  for (int tap = 0; tap < 16; tap++){
    int py = tap >> 2, qx = tap & 3;
#pragma unroll
    for (int step = 0; step < 16; step++){
      int lsub = wave * 16 + step;
      int l = l0 + lsub, co = lane;
      int m = l * 64 + co;
      int c0 = m / 2304, rem = m % 2304, i = rem / 48, jj = rem % 48;
      int Y = 2 * i + py - 1, X = 2 * jj + qx - 1;
      float val = 0.f;
      if ((unsigned)Y < 96u && (unsigned)X < 96u) val = bp[(size_t)c0 * 9216 + Y * 96 + X];
      tile[lsub][co] = f2b(val);
    }
    __syncthreads();
#pragma unroll
    for (int step = 0; step < 16; step++){
      int co = wave * 16 + step;
      rwa[(((size_t)item * 16 + tap) * 64 + co) * 2304 + l0 + lane] = tile[lane][co];
    }
    __syncthreads();
  }
}

// ---------------- deconv: split-K 4-way over (ay,ax), bf16 partials ----------------

__launch_bounds__(256)
__global__ void k_deconv(const uint16_t* __restrict__ rwa, const uint16_t* __restrict__ pt2,
                         uint16_t* __restrict__ part){
  __shared__ __align__(16) uint16_t As[64 * 32];
  __shared__ __align__(16) uint16_t Bs[128 * 32];
  int n0 = blockIdx.x * 128, th = blockIdx.y, z = blockIdx.z;
  int item = z >> 2, phase = z & 3;
  int fy = phase >> 1, fx = phase & 1;
  int ay = th >> 1, ax = th & 1;
  int tid = threadIdx.x, wave = tid >> 6, lane = tid & 63, lm = lane & 15, lg = lane >> 4;
  int swl = (lg ^ ((lm >> 2) & 3)) * 8;
  const uint16_t* Pp = pt2 + (size_t)item * 2500 * 2304;
  int py = 3 - fy - 2 * ay, qx = 3 - fx - 2 * ax;
  const uint16_t* Ap = rwa + ((size_t)item * 16 + py * 4 + qx) * 64 * 2304;
  f32x4 acc[4][2] = {};
  for (int kt = 0; kt < 72; kt++){
    int kb = kt * 32;
#pragma unroll
    for (int c = tid; c < 768; c += 256){
      if (c < 256){
        int row = c >> 2, j = c & 3;
        int sw = (j ^ ((row >> 2) & 3)) * 8;
        gl_lds16(&Ap[(size_t)row * 2304 + kb + sw], &As[c * 8]);
      } else {
        int cc = c - 256; int row = cc >> 2, j = cc & 3;
        int sw = (j ^ ((row >> 2) & 3)) * 8;
        int n = n0 + row; int my = n / 48, mx = n % 48;
        int prow = (my + ay + fy) * 50 + (mx + ax + fx);
        gl_lds16(&Pp[(size_t)prow * 2304 + kb + sw], &Bs[cc * 8]);
      }
    }
    __syncthreads();
    short8 af[4], bf[2];
#pragma unroll
    for (int i = 0; i < 4; i++) af[i] = *(const short8*)&As[(i * 16 + lm) * 32 + swl];
#pragma unroll
    for (int j = 0; j < 2; j++) bf[j] = *(const short8*)&Bs[(wave * 32 + j * 16 + lm) * 32 + swl];
#pragma unroll
    for (int i = 0; i < 4; i++)
#pragma unroll
      for (int j = 0; j < 2; j++)
        acc[i][j] = __builtin_amdgcn_mfma_f32_16x16x32_bf16(af[i], bf[j], acc[i][j], 0, 0, 0);
    __syncthreads();
  }
  uint16_t* pp = part + ((size_t)(th * 16 + z) * 64) * 2304;
#pragma unroll
  for (int i = 0; i < 4; i++)
#pragma unroll
    for (int j = 0; j < 2; j++){
      int n = n0 + wave * 32 + j * 16 + lm;
#pragma unroll
      for (int r = 0; r < 4; r++){
        int co = i * 16 + lg * 4 + r;
        pp[(size_t)co * 2304 + n] = f2b(acc[i][j][r]);
      }
    }
}

__global__ void k_dred(const uint16_t* __restrict__ part, uint16_t* __restrict__ yb){
  int t = threadIdx.x;
  int n = blockIdx.x * 256 + t;
  int co = blockIdx.y, z = blockIdx.z;
  int item = z >> 2, phase = z & 3;
  int fy = phase >> 1, fx = phase & 1;
  size_t idx = ((size_t)z * 64 + co) * 2304 + n;
  const size_t stride = (size_t)16 * 64 * 2304;
  float v = (b2f(part[idx]) + b2f(part[stride + idx]) +
             b2f(part[2 * stride + idx]) + b2f(part[3 * stride + idx])) * 0.25f;
  int my = n / 48, mx = n % 48;
  yb[((size_t)item * 64 + co) * 9216 + (2 * my + fy) * 96 + 2 * mx + fx] = f2b(v);
}

// ---------------- final 3x3 convs ----------------

__global__ void k_pack_w(const float* __restrict__ w1, const float* __restrict__ w2,
                         uint16_t* __restrict__ p1, uint16_t* __restrict__ p2){
  int i = blockIdx.x * 256 + threadIdx.x;
  if (i < 36864){ p1[i] = f2b(w1[i]); p2[i] = f2b(w2[i]); }
}

__global__ void k_im2col(const uint16_t* __restrict__ src, uint16_t* __restrict__ dst){
  int pix = blockIdx.x, item = blockIdx.y, ci = threadIdx.x;
  int y = pix / 96, x = pix % 96;
  const uint16_t* sp = src + ((size_t)item * 64 + ci) * 9216;
  uint16_t* dr = dst + ((size_t)item * 9216 + pix) * 576 + ci * 9;
#pragma unroll
  for (int p = 0; p < 3; p++)
#pragma unroll
    for (int q = 0; q < 3; q++){
      int yy = y + p - 1, xx = x + q - 1;
      dr[p * 3 + q] = ((unsigned)yy < 96u && (unsigned)xx < 96u) ? sp[yy * 96 + xx] : (uint16_t)0;
    }
}

__launch_bounds__(256)
__global__ void k_conv_gemm(const uint16_t* __restrict__ A, const uint16_t* __restrict__ B,
                            const float* __restrict__ bias,
                            uint16_t* __restrict__ dst16, float* __restrict__ dst32){
  __shared__ __align__(16) uint16_t As[64 * 32];
  __shared__ __align__(16) uint16_t Bs[128 * 32];
  int n0 = blockIdx.x * 128, item = blockIdx.z;
  int tid = threadIdx.x, wave = tid >> 6, lane = tid & 63, lm = lane & 15, lg = lane >> 4;
  int swl = (lg ^ ((lm >> 2) & 3)) * 8;
  const uint16_t* Bp = B + (size_t)item * 9216 * 576;
  f32x4 acc[4][2] = {};
  for (int kt = 0; kt < 18; kt++){
    int kb = kt * 32;
#pragma unroll
    for (int c = tid; c < 768; c += 256){
      if (c < 256){
        int row = c >> 2, j = c & 3;
        int sw = (j ^ ((row >> 2) & 3)) * 8;
        gl_lds16(&A[(size_t)row * 576 + kb + sw], &As[c * 8]);
      } else {
        int cc = c - 256; int row = cc >> 2, j = cc & 3;
        int sw = (j ^ ((row >> 2) & 3)) * 8;
        gl_lds16(&Bp[(size_t)(n0 + row) * 576 + kb + sw], &Bs[cc * 8]);
      }
    }
    __syncthreads();
    short8 af[4], bf[2];
#pragma unroll
    for (int i = 0; i < 4; i++) af[i] = *(const short8*)&As[(i * 16 + lm) * 32 + swl];
#pragma unroll
    for (int j = 0; j < 2; j++) bf[j] = *(const short8*)&Bs[(wave * 32 + j * 16 + lm) * 32 + swl];
#pragma unroll
    for (int i = 0; i < 4; i++)
#pragma unroll
      for (int j = 0; j < 2; j++)
        acc[i][j] = __builtin_amdgcn_mfma_f32_16x16x32_bf16(af[i], bf[j], acc[i][j], 0, 0, 0);
    __syncthreads();
  }
#pragma unroll
  for (int i = 0; i < 4; i++)
#pragma unroll
    for (int j = 0; j < 2; j++){
      int n = n0 + wave * 32 + j * 16 + lm;
#pragma unroll
      for (int r = 0; r < 4; r++){
        int co = i * 16 + lg * 4 + r;
        float val = acc[i][j][r] + bias[co];
        if (dst32) dst32[((size_t)item * 64 + co) * 9216 + n] = val;
        else       dst16[((size_t)item * 64 + co) * 9216 + n] = f2b(val);
      }
    }
}

// ---------------- launch ----------------

extern "C" void kernel_launch(void* const* d_in, const int* in_sizes, int n_in,
                              void* d_out, int out_size, void* d_ws, size_t ws_size,
                              hipStream_t stream){
  const float* f  = (const float*)d_in[0];
  const float* b  = (const float*)d_in[1];
  const float* w1 = (const float*)d_in[2];
  const float* b1 = (const float*)d_in[3];
  const float* w2 = (const float*)d_in[4];
  const float* b2 = (const float*)d_in[5];
  char* ws = (char*)d_ws;
  // region A
  float*    Yt   = (float*)ws;                          // 84,934,656 B
  uint16_t* Part = (uint16_t*)ws;                       // 75,497,472 B (over dead Yt)
  uint16_t* Yb   = (uint16_t*)(ws + 75497472ull);       //  4,718,592 B
  uint16_t* Wp1  = (uint16_t*)(ws + 80216064ull);       //     73,728 B
  uint16_t* Wp2  = (uint16_t*)(ws + 80289792ull);       //     73,728 B
  // region B
  uint16_t* Wn   = (uint16_t*)(ws + SZ_BUF);            // 31,850,496 B
  uint16_t* Xb   = Wn + (size_t)4 * 2304 * 1728;        // 31,850,496 B
  uint16_t* Pt2  = (uint16_t*)(ws + SZ_BUF);            // 46,080,000 B (over dead Wn/Xb)
  uint16_t* Rwa  = (uint16_t*)(ws + SZ_BUF + 46080000ull); // 18,874,368 B
  uint16_t* X2   = (uint16_t*)(ws + SZ_BUF);            // 42,467,328 B (over dead Pt2)
  uint16_t* Y1   = (uint16_t*)(ws + SZ_BUF + 42467328ull); // 4,718,592 B
  float*    out  = (float*)d_out;

  k_build_wn<<<dim3(2304, 4), 64, 0, stream>>>(b, Wn);
  k_build_x<<<dim3(2304, 4), 64, 0, stream>>>(f, Xb);
  k_gemm_corr<<<dim3(18, 18, 4), 256, 0, stream>>>(Xb, Wn, Yt);   // A=Xb -> rows=s
  k_zero_pad<<<dim3(196, 4), 256, 0, stream>>>(Pt2);              // Wn/Xb dead now
  k_build_rwa<<<dim3(36, 4), 256, 0, stream>>>(b, Rwa);
  k_fuse_sm<<<dim3(2304, 4), 256, 0, stream>>>(Yt, Pt2);
  k_deconv<<<dim3(18, 4, 16), 256, 0, stream>>>(Rwa, Pt2, Part);  // Yt dead now
  k_dred<<<dim3(9, 64, 16), 256, 0, stream>>>(Part, Yb);
  k_pack_w<<<dim3(144), 256, 0, stream>>>(w1, w2, Wp1, Wp2);
  k_im2col<<<dim3(9216, 4), 64, 0, stream>>>(Yb, X2);             // Pt2/Rwa dead now
  k_conv_gemm<<<dim3(72, 1, 4), 256, 0, stream>>>(Wp1, X2, b1, Y1, nullptr);
  k_im2col<<<dim3(9216, 4), 64, 0, stream>>>(Y1, X2);
  k_conv_gemm<<<dim3(72, 1, 4), 256, 0, stream>>>(Wp2, X2, b2, nullptr, out);
}

// Round 6
// 513.889 us; speedup vs baseline: 2.0388x; 1.4014x over previous
//
#include <hip/hip_runtime.h>
#include <stdint.h>

// ContextualAttention on MI355X. Inputs/outputs float32; internals split-bf16 MFMA
// for correlation logits, plain bf16 MFMA elsewhere, fp32 fuse/softmax.
//
// Round 6 changes:
//  - deconv reformulated as ONE GEMM: T[tap*64+co][sp] = Rwa[m][l] . Pt2[sp][l],
//    M=1024, N=2560 (padded 50x50), K=2304 -> full 128x128 MFMA tile (k_deconv2),
//    then k_dred2 4-tap gather. Kills 75.5 MB partial write+read.
//  - im2col eliminated: weights repacked to K-order t*64+ci; deconv/conv1 outputs in
//    zero-padded pixel-major channel-minor [98][98][64] bf16 -> conv B-tiles staged
//    directly with global_load_lds (16B contiguous along ci, always in-bounds).
//
// ws layout (bytes), total <= 169,869,312:
//  region A [0, 84934656):
//    phase1: Yt f32 (84,934,656)
//    phase2 (after fuse_sm): T bf16 [0, 20971520) | Ybt2 [20971520, +4917248)
//            | Y1t2 [25888768, +4917248) | Wp1 [30806016, +73728) | Wp2 [30879744, +73728)
//  region B [84934656, ...):
//    phase1: Wn (31850496) + Xb (31850496)
//    phase2: Pt2 bf16 [SZ_BUF, +46080000) | Rwa [+46080000, +18874368)

#define SZ_BUF 84934656ull
typedef __attribute__((ext_vector_type(8))) short short8;
typedef __attribute__((ext_vector_type(4))) float f32x4;
typedef __attribute__((ext_vector_type(4), aligned(4))) float f32x4u;
typedef __attribute__((ext_vector_type(4))) short s16x4;

#if defined(__has_builtin)
#if __has_builtin(__builtin_amdgcn_global_load_lds)
#define HAVE_GLL 1
#endif
#endif

#ifdef HAVE_GLL
typedef const __attribute__((address_space(1))) void* gp1_t;
typedef __attribute__((address_space(3))) void* lp3_t;
__device__ __forceinline__ void gl_lds16(const void* g, void* l){
  __builtin_amdgcn_global_load_lds((gp1_t)g, (lp3_t)l, 16, 0, 0);
}
#else
__device__ __forceinline__ void gl_lds16(const void* g, void* l){
  *(short8*)l = *(const short8*)g;
}
#endif

__device__ __forceinline__ float b2f(uint16_t u){
  union { uint32_t i; float f; } v; v.i = ((uint32_t)u) << 16; return v.f;
}
__device__ __forceinline__ uint16_t f2b(float f){
  uint32_t x = __float_as_uint(f);
  uint32_t r = (x + 0x7FFFu + ((x >> 16) & 1u)) >> 16;
  return (uint16_t)r;
}
__device__ __forceinline__ int gfun(int x, int d){
  int t = (x % 48) * 48 + (x / 48) + d;
  if ((unsigned)t >= 2304u) return -1;
  return (t % 48) * 48 + (t / 48);
}

// ---------------- prep kernels ----------------

__global__ void k_build_wn(const float* __restrict__ bsrc, uint16_t* __restrict__ wn){
  int o = blockIdx.x, item = blockIdx.y, c = threadIdx.x;
  int m = o * 64 + c;
  int c0 = m / 2304, rem = m % 2304, i = rem / 48, j = rem % 48;
  const float* bp = bsrc + ((size_t)item * 64 + c0) * 9216;
  float v[9]; float ss = 0.f;
#pragma unroll
  for (int p = 0; p < 3; p++)
#pragma unroll
    for (int q = 0; q < 3; q++){
      int y = i + p - 1, x = j + q - 1;
      float val = 0.f;
      if ((unsigned)y < 48u && (unsigned)x < 48u) val = bp[y * 192 + x * 2];
      v[p * 3 + q] = val; ss += val * val;
    }
#pragma unroll
  for (int off = 32; off > 0; off >>= 1) ss += __shfl_xor(ss, off, 64);
  float inv = 1.f / fmaxf(sqrtf(ss), 1e-4f);
  uint16_t* wr = wn + ((size_t)item * 2304 + o) * 1728;
#pragma unroll
  for (int t = 0; t < 9; t++){
    float fv = v[t] * inv;
    uint16_t hi = f2b(fv);
    uint16_t lo = f2b(fv - b2f(hi));
    wr[c * 9 + t] = hi;            // block 0: w_hi (x x_hi)
    wr[576 + c * 9 + t] = hi;      // block 1: w_hi (x x_lo)
    wr[1152 + c * 9 + t] = lo;     // block 2: w_lo (x x_hi)
  }
}

__global__ void k_build_x(const float* __restrict__ fsrc, uint16_t* __restrict__ xb){
  int s = blockIdx.x, item = blockIdx.y, c = threadIdx.x;
  int y = s / 48, x = s % 48;
  const float* fp = fsrc + ((size_t)item * 64 + c) * 9216;
  uint16_t* xr = xb + ((size_t)item * 2304 + s) * 1728;
#pragma unroll
  for (int p = 0; p < 3; p++)
#pragma unroll
    for (int q = 0; q < 3; q++){
      int yy = y + p - 1, xx = x + q - 1;
      float val = 0.f;
      if ((unsigned)yy < 48u && (unsigned)xx < 48u) val = fp[yy * 192 + xx * 2];
      uint16_t hi = f2b(val);
      uint16_t lo = f2b(val - b2f(hi));
      int t = p * 3 + q;
      xr[c * 9 + t] = hi;
      xr[576 + c * 9 + t] = lo;
      xr[1152 + c * 9 + t] = hi;
    }
}

// ---------------- correlation GEMM: Yt[s][o] = X @ Wn^T, M=N=2304, K=1728 ----------------

__launch_bounds__(256)
__global__ void k_gemm_corr(const uint16_t* __restrict__ A, const uint16_t* __restrict__ B,
                            float* __restrict__ Cd){
  __shared__ __align__(16) uint16_t As[128 * 32];
  __shared__ __align__(16) uint16_t Bs[128 * 32];
  int item = blockIdx.z;
  int n0 = blockIdx.x * 128, m0 = blockIdx.y * 128;
  const uint16_t* Ap = A + (size_t)item * 2304 * 1728;
  const uint16_t* Bp = B + (size_t)item * 2304 * 1728;
  int tid = threadIdx.x;
  int wave = tid >> 6, lane = tid & 63, lm = lane & 15, lg = lane >> 4;
  int wy = wave >> 1, wx = wave & 1;
  int swl = (lg ^ ((lm >> 2) & 3)) * 8;
  f32x4 acc[4][4] = {};
  for (int kt = 0; kt < 54; kt++){
    int kb = kt * 32;
#pragma unroll
    for (int c = tid; c < 1024; c += 256){
      int cc = c & 511;
      int row = cc >> 2, j = cc & 3;
      int sw = (j ^ ((row >> 2) & 3)) * 8;
      if (c < 512)
        gl_lds16(&Ap[(size_t)(m0 + row) * 1728 + kb + sw], &As[cc * 8]);
      else
        gl_lds16(&Bp[(size_t)(n0 + row) * 1728 + kb + sw], &Bs[cc * 8]);
    }
    __syncthreads();
    short8 af[4], bf[4];
#pragma unroll
    for (int i = 0; i < 4; i++){
      af[i] = *(const short8*)&As[(wy * 64 + i * 16 + lm) * 32 + swl];
      bf[i] = *(const short8*)&Bs[(wx * 64 + i * 16 + lm) * 32 + swl];
    }
#pragma unroll
    for (int i = 0; i < 4; i++)
#pragma unroll
      for (int j = 0; j < 4; j++)
        acc[i][j] = __builtin_amdgcn_mfma_f32_16x16x32_bf16(af[i], bf[j], acc[i][j], 0, 0, 0);
    __syncthreads();
  }
  float* Cp = Cd + (size_t)item * 2304 * 2304;
#pragma unroll
  for (int i = 0; i < 4; i++){
    int rb = m0 + wy * 64 + i * 16 + lg * 4;
#pragma unroll
    for (int j = 0; j < 4; j++){
      int cc = n0 + wx * 64 + j * 16 + lm;
#pragma unroll
      for (int r = 0; r < 4; r++)
        Cp[(size_t)(rb + r) * 2304 + cc] = acc[i][j][r];
    }
  }
}

// ---------------- merged fuse + softmax (vectorized) ----------------

__global__ void k_fuse_sm(const float* __restrict__ Yt, uint16_t* __restrict__ pt2){
  __shared__ float red[4];
  int s = blockIdx.x, item = blockIdx.y, t = threadIdx.x;
  const float* yp = Yt + (size_t)item * 2304 * 2304;
  int rs[3]; rs[0] = gfun(s, -1); rs[1] = s; rs[2] = gfun(s, 1);
  int nact = (t < 64) ? 3 : 2;
  f32x4u v[3];
  for (int u = 0; u < 3; u++){
    f32x4u acc = {0.f, 0.f, 0.f, 0.f};
    if (u < nact){
      int g = t + u * 256;
      int o0 = 4 * g, orr = o0 / 48, oc0 = o0 % 48;
#pragma unroll
      for (int dd = 0; dd < 3; dd++){
        int a0 = rs[dd];
        if (a0 < 0) continue;
        int d = dd - 1;
        int base; int vm = 0xF;
        if (d == 0) base = o0;
        else {
          int tor = orr + d;
          if ((unsigned)tor < 48u) base = tor * 48 + oc0;
          else if (tor < 0){ base = 2255 + oc0; if (oc0 == 0) vm = 0xE; }
          else { base = oc0 + 1; if (oc0 == 44) vm = 0x7; }
        }
#pragma unroll
        for (int e = -1; e <= 1; e++){
          int a = a0 + e;
          if ((unsigned)a >= 2304u) continue;
          int cb = base + e;
          const float* rowp = yp + (size_t)a * 2304;
          if (vm == 0xF && cb >= 0 && cb + 3 < 2304){
            acc += *(const f32x4u*)&rowp[cb];
          } else {
#pragma unroll
            for (int i = 0; i < 4; i++)
              if ((vm >> i) & 1){
                int c2 = cb + i;
                if ((unsigned)c2 < 2304u) acc[i] += rowp[c2];
              }
          }
        }
      }
    }
    v[u] = acc;
  }
  float mx = -3.4e38f;
  for (int u = 0; u < nact; u++)
#pragma unroll
    for (int i = 0; i < 4; i++) mx = fmaxf(mx, v[u][i]);
#pragma unroll
  for (int off = 32; off > 0; off >>= 1) mx = fmaxf(mx, __shfl_xor(mx, off, 64));
  if ((t & 63) == 0) red[t >> 6] = mx;
  __syncthreads();
  mx = fmaxf(fmaxf(red[0], red[1]), fmaxf(red[2], red[3]));
  float sum = 0.f;
  for (int u = 0; u < nact; u++)
#pragma unroll
    for (int i = 0; i < 4; i++){ v[u][i] = __expf(10.f * (v[u][i] - mx)); sum += v[u][i]; }
#pragma unroll
  for (int off = 32; off > 0; off >>= 1) sum += __shfl_xor(sum, off, 64);
  __syncthreads();
  if ((t & 63) == 0) red[t >> 6] = sum;
  __syncthreads();
  float inv = 1.f / (red[0] + red[1] + red[2] + red[3]);
  uint16_t* pr = pt2 + ((size_t)item * 2500 + (size_t)(s / 48 + 1) * 50 + (s % 48) + 1) * 2304;
  for (int u = 0; u < nact; u++){
    s16x4 w;
#pragma unroll
    for (int i = 0; i < 4; i++) w[i] = (short)f2b(v[u][i] * inv);
    *(s16x4*)&pr[4 * (t + u * 256)] = w;
  }
}

__global__ void k_zero_pad(uint16_t* __restrict__ pt2){
  int p = blockIdx.x, item = blockIdx.y, t = threadIdx.x;
  int sy, sx;
  if (p < 50){ sy = 0; sx = p; }
  else if (p < 100){ sy = 49; sx = p - 50; }
  else if (p < 148){ sy = p - 99; sx = 0; }
  else { sy = p - 147; sx = 49; }
  uint16_t* pr = pt2 + ((size_t)item * 2500 + sy * 50 + sx) * 2304;
  short8 z = {};
  for (int c = t; c < 288; c += 256) *(short8*)&pr[c * 8] = z;
}

// ---------------- raw 4x4 patch bank, layout [item][tap16][co][l] ----------------

__global__ void k_build_rwa(const float* __restrict__ bsrc, uint16_t* __restrict__ rwa){
  __shared__ uint16_t tile[64][66];
  int item = blockIdx.y, l0 = blockIdx.x * 64;
  const float* bp = bsrc + (size_t)item * 64 * 9216;
  int wave = threadIdx.x >> 6, lane = threadIdx.x & 63;
  for (int tap = 0; tap < 16; tap++){
    int py = tap >> 2, qx = tap & 3;
#pragma unroll
    for (int step = 0; step < 16; step++){
      int lsub = wave * 16 + step;
      int l = l0 + lsub, co = lane;
      int m = l * 64 + co;
      int c0 = m / 2304, rem = m % 2304, i = rem / 48, jj = rem % 48;
      int Y = 2 * i + py - 1, X = 2 * jj + qx - 1;
      float val = 0.f;
      if ((unsigned)Y < 96u && (unsigned)X < 96u) val = bp[(size_t)c0 * 9216 + Y * 96 + X];
      tile[lsub][co] = f2b(val);
    }
    __syncthreads();
#pragma unroll
    for (int step = 0; step < 16; step++){
      int co = wave * 16 + step;
      rwa[(((size_t)item * 16 + tap) * 64 + co) * 2304 + l0 + lane] = tile[lane][co];
    }
    __syncthreads();
  }
}

// ---------------- deconv GEMM: T[m=tap*64+co][sp] = Rwa . Pt2^T, M=1024,N=2560,K=2304 ----------------

__launch_bounds__(256)
__global__ void k_deconv2(const uint16_t* __restrict__ rwa, const uint16_t* __restrict__ pt2,
                          uint16_t* __restrict__ T){
  __shared__ __align__(16) uint16_t As[128 * 32];
  __shared__ __align__(16) uint16_t Bs[128 * 32];
  int item = blockIdx.z;
  int n0 = blockIdx.x * 128, m0 = blockIdx.y * 128;
  const uint16_t* Ap = rwa + (size_t)item * 1024 * 2304;
  const uint16_t* Bp = pt2 + (size_t)item * 2500 * 2304;   // rows up to 2559 read garbage; discarded
  int tid = threadIdx.x;
  int wave = tid >> 6, lane = tid & 63, lm = lane & 15, lg = lane >> 4;
  int wy = wave >> 1, wx = wave & 1;
  int swl = (lg ^ ((lm >> 2) & 3)) * 8;
  f32x4 acc[4][4] = {};
  for (int kt = 0; kt < 72; kt++){
    int kb = kt * 32;
#pragma unroll
    for (int c = tid; c < 1024; c += 256){
      int cc = c & 511;
      int row = cc >> 2, j = cc & 3;
      int sw = (j ^ ((row >> 2) & 3)) * 8;
      if (c < 512)
        gl_lds16(&Ap[(size_t)(m0 + row) * 2304 + kb + sw], &As[cc * 8]);
      else
        gl_lds16(&Bp[(size_t)(n0 + row) * 2304 + kb + sw], &Bs[cc * 8]);
    }
    __syncthreads();
    short8 af[4], bf[4];
#pragma unroll
    for (int i = 0; i < 4; i++){
      af[i] = *(const short8*)&As[(wy * 64 + i * 16 + lm) * 32 + swl];
      bf[i] = *(const short8*)&Bs[(wx * 64 + i * 16 + lm) * 32 + swl];
    }
#pragma unroll
    for (int i = 0; i < 4; i++)
#pragma unroll
      for (int j = 0; j < 4; j++)
        acc[i][j] = __builtin_amdgcn_mfma_f32_16x16x32_bf16(af[i], bf[j], acc[i][j], 0, 0, 0);
    __syncthreads();
  }
  uint16_t* Tp = T + (size_t)item * 1024 * 2560;
#pragma unroll
  for (int i = 0; i < 4; i++){
    int rb = m0 + wy * 64 + i * 16 + lg * 4;
#pragma unroll
    for (int j = 0; j < 4; j++){
      int cc = n0 + wx * 64 + j * 16 + lm;
#pragma unroll
      for (int r = 0; r < 4; r++)
        Tp[(size_t)(rb + r) * 2560 + cc] = f2b(acc[i][j][r]);
    }
  }
}

// gather 4 taps per output pixel -> padded Ybt2[98][98][64] interior
__global__ void k_dred2(const uint16_t* __restrict__ T, uint16_t* __restrict__ ybt2){
  int my = blockIdx.x, phase = blockIdx.y, item = blockIdx.z;
  int co = threadIdx.x;
  int fy = phase >> 1, fx = phase & 1;
  const uint16_t* Tp = T + (size_t)item * 1024 * 2560;
  uint16_t* op = ybt2 + (size_t)item * 98 * 98 * 64;
  for (int mx = 0; mx < 48; mx++){
    float acc = 0.f;
#pragma unroll
    for (int ay = 0; ay < 2; ay++)
#pragma unroll
      for (int ax = 0; ax < 2; ax++){
        int tap = (3 - fy - 2 * ay) * 4 + (3 - fx - 2 * ax);
        int sp = (my + ay + fy) * 50 + (mx + ax + fx);
        acc += b2f(Tp[(size_t)(tap * 64 + co) * 2560 + sp]);
      }
    int Y = 2 * my + fy + 1, X = 2 * mx + fx + 1;
    op[((size_t)Y * 98 + X) * 64 + co] = f2b(acc * 0.25f);
  }
}

__global__ void k_zero2(uint16_t* __restrict__ p){
  size_t i = ((size_t)blockIdx.x * 256 + threadIdx.x) * 8;
  short8 z = {};
  *(short8*)&p[i] = z;
}

// ---------------- final 3x3 convs (direct from padded layout) ----------------

// repack w[co][ci][p][q] -> Wp[co][t*64+ci], t=p*3+q
__global__ void k_pack_w(const float* __restrict__ w1, const float* __restrict__ w2,
                         uint16_t* __restrict__ p1, uint16_t* __restrict__ p2){
  int i = blockIdx.x * 256 + threadIdx.x;
  if (i < 36864){
    int co = i / 576, rem = i % 576, ci = rem / 9, t = rem % 9;
    int di = co * 576 + t * 64 + ci;
    p1[di] = f2b(w1[i]); p2[di] = f2b(w2[i]);
  }
}

// C[co][pix] = sum_k Wp[co][k] * Src[(y+py)*98 + x+qx][ci],  k = t*64+ci
__launch_bounds__(256)
__global__ void k_conv_gemm2(const uint16_t* __restrict__ Wp, const uint16_t* __restrict__ Src,
                             const float* __restrict__ bias,
                             uint16_t* __restrict__ dst16, float* __restrict__ dst32){
  __shared__ __align__(16) uint16_t As[64 * 32];
  __shared__ __align__(16) uint16_t Bs[128 * 32];
  int n0 = blockIdx.x * 128, item = blockIdx.z;
  int tid = threadIdx.x, wave = tid >> 6, lane = tid & 63, lm = lane & 15, lg = lane >> 4;
  int swl = (lg ^ ((lm >> 2) & 3)) * 8;
  const uint16_t* Bp = Src + (size_t)item * 98 * 98 * 64;
  f32x4 acc[4][2] = {};
  for (int kt = 0; kt < 18; kt++){
    int t = kt >> 1, cb = (kt & 1) * 32;
    int py = t / 3, qx = t % 3;
#pragma unroll
    for (int c = tid; c < 768; c += 256){
      if (c < 256){
        int row = c >> 2, j = c & 3;
        int sw = (j ^ ((row >> 2) & 3)) * 8;
        gl_lds16(&Wp[(size_t)row * 576 + kt * 32 + sw], &As[c * 8]);
      } else {
        int cc = c - 256; int row = cc >> 2, j = cc & 3;
        int sw = (j ^ ((row >> 2) & 3)) * 8;
        int n = n0 + row; int y = n / 96, x = n % 96;
        gl_lds16(&Bp[((size_t)(y + py) * 98 + (x + qx)) * 64 + cb + sw], &Bs[cc * 8]);
      }
    }
    __syncthreads();
    short8 af[4], bf[2];
#pragma unroll
    for (int i = 0; i < 4; i++) af[i] = *(const short8*)&As[(i * 16 + lm) * 32 + swl];
#pragma unroll
    for (int j = 0; j < 2; j++) bf[j] = *(const short8*)&Bs[(wave * 32 + j * 16 + lm) * 32 + swl];
#pragma unroll
    for (int i = 0; i < 4; i++)
#pragma unroll
      for (int j = 0; j < 2; j++)
        acc[i][j] = __builtin_amdgcn_mfma_f32_16x16x32_bf16(af[i], bf[j], acc[i][j], 0, 0, 0);
    __syncthreads();
  }
  if (dst32){
#pragma unroll
    for (int i = 0; i < 4; i++)
#pragma unroll
      for (int j = 0; j < 2; j++){
        int n = n0 + wave * 32 + j * 16 + lm;
#pragma unroll
        for (int r = 0; r < 4; r++){
          int co = i * 16 + lg * 4 + r;
          dst32[((size_t)item * 64 + co) * 9216 + n] = acc[i][j][r] + bias[co];
        }
      }
  } else {
    uint16_t* dp = dst16 + (size_t)item * 98 * 98 * 64;
#pragma unroll
    for (int i = 0; i < 4; i++)
#pragma unroll
      for (int j = 0; j < 2; j++){
        int n = n0 + wave * 32 + j * 16 + lm;
        int y = n / 96, x = n % 96;
        int co0 = i * 16 + lg * 4;
        s16x4 w;
#pragma unroll
        for (int r = 0; r < 4; r++) w[r] = (short)f2b(acc[i][j][r] + bias[co0 + r]);
        *(s16x4*)&dp[((size_t)(y + 1) * 98 + (x + 1)) * 64 + co0] = w;
      }
  }
}

// ---------------- launch ----------------

extern "C" void kernel_launch(void* const* d_in, const int* in_sizes, int n_in,
                              void* d_out, int out_size, void* d_ws, size_t ws_size,
                              hipStream_t stream){
  const float* f  = (const float*)d_in[0];
  const float* b  = (const float*)d_in[1];
  const float* w1 = (const float*)d_in[2];
  const float* b1 = (const float*)d_in[3];
  const float* w2 = (const float*)d_in[4];
  const float* b2 = (const float*)d_in[5];
  char* ws = (char*)d_ws;
  // region A
  float*    Yt   = (float*)ws;                          // 84,934,656 B (phase1)
  uint16_t* T    = (uint16_t*)ws;                       // 20,971,520 B (over dead Yt)
  uint16_t* Ybt2 = (uint16_t*)(ws + 20971520ull);       //  4,917,248 B
  uint16_t* Y1t2 = (uint16_t*)(ws + 25888768ull);       //  4,917,248 B
  uint16_t* Wp1  = (uint16_t*)(ws + 30806016ull);       //     73,728 B
  uint16_t* Wp2  = (uint16_t*)(ws + 30879744ull);       //     73,728 B
  // region B
  uint16_t* Wn   = (uint16_t*)(ws + SZ_BUF);            // 31,850,496 B
  uint16_t* Xb   = Wn + (size_t)4 * 2304 * 1728;        // 31,850,496 B
  uint16_t* Pt2  = (uint16_t*)(ws + SZ_BUF);            // 46,080,000 B (over dead Wn/Xb)
  uint16_t* Rwa  = (uint16_t*)(ws + SZ_BUF + 46080000ull); // 18,874,368 B
  float*    out  = (float*)d_out;

  k_build_wn<<<dim3(2304, 4), 64, 0, stream>>>(b, Wn);
  k_build_x<<<dim3(2304, 4), 64, 0, stream>>>(f, Xb);
  k_gemm_corr<<<dim3(18, 18, 4), 256, 0, stream>>>(Xb, Wn, Yt);   // A=Xb -> rows=s
  k_zero_pad<<<dim3(196, 4), 256, 0, stream>>>(Pt2);              // Wn/Xb dead now
  k_build_rwa<<<dim3(36, 4), 256, 0, stream>>>(b, Rwa);
  k_fuse_sm<<<dim3(2304, 4), 256, 0, stream>>>(Yt, Pt2);
  k_deconv2<<<dim3(20, 8, 4), 256, 0, stream>>>(Rwa, Pt2, T);     // Yt dead now
  k_zero2<<<dim3(2401), 256, 0, stream>>>(Ybt2);                  // zeroes Ybt2+Y1t2 (contiguous)
  k_dred2<<<dim3(48, 4, 4), 64, 0, stream>>>(T, Ybt2);
  k_pack_w<<<dim3(144), 256, 0, stream>>>(w1, w2, Wp1, Wp2);
  k_conv_gemm2<<<dim3(72, 1, 4), 256, 0, stream>>>(Wp1, Ybt2, b1, Y1t2, nullptr);
  k_conv_gemm2<<<dim3(72, 1, 4), 256, 0, stream>>>(Wp2, Y1t2, b2, nullptr, out);
}

// Round 8
// 461.110 us; speedup vs baseline: 2.2722x; 1.1145x over previous
//
#include <hip/hip_runtime.h>
#include <stdint.h>

// ContextualAttention on MI355X. Inputs/outputs float32; correlation logits via
// 2-term f16 split MFMA: A = x-patches [x_hi | x_lo] (K=1152), B = w-patches w_hi
// only (576, staged twice per K-sweep) -> product = x . w_hi (error only from w's
// 2^-11 rounding). Plain bf16 MFMA elsewhere, fp32 fuse/softmax.
//
// Round 8 changes (fix of round-7 stride-mismatch bug):
//  - k_build_x now emits [hi|lo] at stride 1152 (matches gemm A operand)
//  - k_build_wn now emits hi-only at stride 576 (matches gemm B operand)
//  - ws offsets updated (Wn 10.6 MB, Xb 21.2 MB)
//
// ws layout (bytes), total <= 169,869,312:
//  region A [0, 84934656):
//    phase1: Yt f32 (84,934,656)
//    phase2: T bf16 [0, 20971520) | Ybt2 [20971520, +4917248) | Y1t2 [25888768, +4917248)
//            | Wp1 [30806016, +73728) | Wp2 [30879744, +73728)
//  region B [84934656, ...):
//    phase1: Wn f16 (10,616,832) + Xb f16 (21,233,664)
//    phase2: Pt2 bf16 [SZ_BUF, +46080000) | Rwa [+46080000, +18874368)

#define SZ_BUF 84934656ull
typedef __attribute__((ext_vector_type(8))) short short8;
typedef __attribute__((ext_vector_type(8))) _Float16 half8;
typedef __attribute__((ext_vector_type(4))) float f32x4;
typedef __attribute__((ext_vector_type(4), aligned(4))) float f32x4u;
typedef __attribute__((ext_vector_type(4))) short s16x4;

#if defined(__has_builtin)
#if __has_builtin(__builtin_amdgcn_global_load_lds)
#define HAVE_GLL 1
#endif
#endif

#ifdef HAVE_GLL
typedef const __attribute__((address_space(1))) void* gp1_t;
typedef __attribute__((address_space(3))) void* lp3_t;
__device__ __forceinline__ void gl_lds16(const void* g, void* l){
  __builtin_amdgcn_global_load_lds((gp1_t)g, (lp3_t)l, 16, 0, 0);
}
#else
__device__ __forceinline__ void gl_lds16(const void* g, void* l){
  *(short8*)l = *(const short8*)g;
}
#endif

__device__ __forceinline__ float b2f(uint16_t u){
  union { uint32_t i; float f; } v; v.i = ((uint32_t)u) << 16; return v.f;
}
__device__ __forceinline__ uint16_t f2b(float f){
  uint32_t x = __float_as_uint(f);
  uint32_t r = (x + 0x7FFFu + ((x >> 16) & 1u)) >> 16;
  return (uint16_t)r;
}
__device__ __forceinline__ uint16_t f2h(float f){
  union { _Float16 h; uint16_t u; } v; v.h = (_Float16)f; return v.u;
}
__device__ __forceinline__ float h2f(uint16_t u){
  union { uint16_t u; _Float16 h; } v; v.u = u; return (float)v.h;
}
__device__ __forceinline__ int gfun(int x, int d){
  int t = (x % 48) * 48 + (x / 48) + d;
  if ((unsigned)t >= 2304u) return -1;
  return (t % 48) * 48 + (t / 48);
}

// ---------------- prep kernels ----------------

// normalized 3x3 patch bank, w_hi only (f16), stride 576  -> GEMM B operand
__global__ void k_build_wn(const float* __restrict__ bsrc, uint16_t* __restrict__ wn){
  int o = blockIdx.x, item = blockIdx.y, c = threadIdx.x;
  int m = o * 64 + c;
  int c0 = m / 2304, rem = m % 2304, i = rem / 48, j = rem % 48;
  const float* bp = bsrc + ((size_t)item * 64 + c0) * 9216;
  float v[9]; float ss = 0.f;
#pragma unroll
  for (int p = 0; p < 3; p++)
#pragma unroll
    for (int q = 0; q < 3; q++){
      int y = i + p - 1, x = j + q - 1;
      float val = 0.f;
      if ((unsigned)y < 48u && (unsigned)x < 48u) val = bp[y * 192 + x * 2];
      v[p * 3 + q] = val; ss += val * val;
    }
#pragma unroll
  for (int off = 32; off > 0; off >>= 1) ss += __shfl_xor(ss, off, 64);
  float inv = 1.f / fmaxf(sqrtf(ss), 1e-4f);
  uint16_t* wr = wn + ((size_t)item * 2304 + o) * 576;
#pragma unroll
  for (int t = 0; t < 9; t++) wr[c * 9 + t] = f2h(v[t] * inv);
}

// im2col of fd, [x_hi | x_lo] f16, stride 1152  -> GEMM A operand
__global__ void k_build_x(const float* __restrict__ fsrc, uint16_t* __restrict__ xb){
  int s = blockIdx.x, item = blockIdx.y, c = threadIdx.x;
  int y = s / 48, x = s % 48;
  const float* fp = fsrc + ((size_t)item * 64 + c) * 9216;
  uint16_t* xr = xb + ((size_t)item * 2304 + s) * 1152;
#pragma unroll
  for (int p = 0; p < 3; p++)
#pragma unroll
    for (int q = 0; q < 3; q++){
      int yy = y + p - 1, xx = x + q - 1;
      float val = 0.f;
      if ((unsigned)yy < 48u && (unsigned)xx < 48u) val = fp[yy * 192 + xx * 2];
      uint16_t hi = f2h(val);
      int t = p * 3 + q;
      xr[c * 9 + t] = hi;                       // block 0: x_hi
      xr[576 + c * 9 + t] = f2h(val - h2f(hi)); // block 1: x_lo
    }
}

// ---------------- correlation GEMM: Yt[s][o] = X @ Wn^T, M=N=2304, K=1152 (f16) ----------------
// A rows (stride 1152): [x_hi | x_lo]; B rows (stride 576): w_hi, staged for both halves.

__launch_bounds__(256)
__global__ void k_gemm_corr(const uint16_t* __restrict__ A, const uint16_t* __restrict__ B,
                            float* __restrict__ Cd){
  __shared__ __align__(16) uint16_t As[128 * 32];
  __shared__ __align__(16) uint16_t Bs[128 * 32];
  int item = blockIdx.z;
  int n0 = blockIdx.x * 128, m0 = blockIdx.y * 128;
  const uint16_t* Ap = A + (size_t)item * 2304 * 1152;
  const uint16_t* Bp = B + (size_t)item * 2304 * 576;
  int tid = threadIdx.x;
  int wave = tid >> 6, lane = tid & 63, lm = lane & 15, lg = lane >> 4;
  int wy = wave >> 1, wx = wave & 1;
  int swl = (lg ^ ((lm >> 2) & 3)) * 8;
  f32x4 acc[4][4] = {};
  for (int kt = 0; kt < 36; kt++){
    int kb = kt * 32;
    int bkb = (kt < 18) ? kb : kb - 576;
#pragma unroll
    for (int c = tid; c < 1024; c += 256){
      int cc = c & 511;
      int row = cc >> 2, j = cc & 3;
      int sw = (j ^ ((row >> 2) & 3)) * 8;
      if (c < 512)
        gl_lds16(&Ap[(size_t)(m0 + row) * 1152 + kb + sw], &As[cc * 8]);
      else
        gl_lds16(&Bp[(size_t)(n0 + row) * 576 + bkb + sw], &Bs[cc * 8]);
    }
    __syncthreads();
    half8 af[4], bf[4];
#pragma unroll
    for (int i = 0; i < 4; i++){
      af[i] = *(const half8*)&As[(wy * 64 + i * 16 + lm) * 32 + swl];
      bf[i] = *(const half8*)&Bs[(wx * 64 + i * 16 + lm) * 32 + swl];
    }
#pragma unroll
    for (int i = 0; i < 4; i++)
#pragma unroll
      for (int j = 0; j < 4; j++)
        acc[i][j] = __builtin_amdgcn_mfma_f32_16x16x32_f16(af[i], bf[j], acc[i][j], 0, 0, 0);
    __syncthreads();
  }
  float* Cp = Cd + (size_t)item * 2304 * 2304;
#pragma unroll
  for (int i = 0; i < 4; i++){
    int rb = m0 + wy * 64 + i * 16 + lg * 4;
#pragma unroll
    for (int j = 0; j < 4; j++){
      int cc = n0 + wx * 64 + j * 16 + lm;
#pragma unroll
      for (int r = 0; r < 4; r++)
        Cp[(size_t)(rb + r) * 2304 + cc] = acc[i][j][r];
    }
  }
}

// ---------------- merged fuse + softmax (vectorized) ----------------

__global__ void k_fuse_sm(const float* __restrict__ Yt, uint16_t* __restrict__ pt2){
  __shared__ float red[4];
  int s = blockIdx.x, item = blockIdx.y, t = threadIdx.x;
  const float* yp = Yt + (size_t)item * 2304 * 2304;
  int rs[3]; rs[0] = gfun(s, -1); rs[1] = s; rs[2] = gfun(s, 1);
  int nact = (t < 64) ? 3 : 2;
  f32x4u v[3];
  for (int u = 0; u < 3; u++){
    f32x4u acc = {0.f, 0.f, 0.f, 0.f};
    if (u < nact){
      int g = t + u * 256;
      int o0 = 4 * g, orr = o0 / 48, oc0 = o0 % 48;
#pragma unroll
      for (int dd = 0; dd < 3; dd++){
        int a0 = rs[dd];
        if (a0 < 0) continue;
        int d = dd - 1;
        int base; int vm = 0xF;
        if (d == 0) base = o0;
        else {
          int tor = orr + d;
          if ((unsigned)tor < 48u) base = tor * 48 + oc0;
          else if (tor < 0){ base = 2255 + oc0; if (oc0 == 0) vm = 0xE; }
          else { base = oc0 + 1; if (oc0 == 44) vm = 0x7; }
        }
#pragma unroll
        for (int e = -1; e <= 1; e++){
          int a = a0 + e;
          if ((unsigned)a >= 2304u) continue;
          int cb = base + e;
          const float* rowp = yp + (size_t)a * 2304;
          if (vm == 0xF && cb >= 0 && cb + 3 < 2304){
            acc += *(const f32x4u*)&rowp[cb];
          } else {
#pragma unroll
            for (int i = 0; i < 4; i++)
              if ((vm >> i) & 1){
                int c2 = cb + i;
                if ((unsigned)c2 < 2304u) acc[i] += rowp[c2];
              }
          }
        }
      }
    }
    v[u] = acc;
  }
  float mx = -3.4e38f;
  for (int u = 0; u < nact; u++)
#pragma unroll
    for (int i = 0; i < 4; i++) mx = fmaxf(mx, v[u][i]);
#pragma unroll
  for (int off = 32; off > 0; off >>= 1) mx = fmaxf(mx, __shfl_xor(mx, off, 64));
  if ((t & 63) == 0) red[t >> 6] = mx;
  __syncthreads();
  mx = fmaxf(fmaxf(red[0], red[1]), fmaxf(red[2], red[3]));
  float sum = 0.f;
  for (int u = 0; u < nact; u++)
#pragma unroll
    for (int i = 0; i < 4; i++){ v[u][i] = __expf(10.f * (v[u][i] - mx)); sum += v[u][i]; }
#pragma unroll
  for (int off = 32; off > 0; off >>= 1) sum += __shfl_xor(sum, off, 64);
  __syncthreads();
  if ((t & 63) == 0) red[t >> 6] = sum;
  __syncthreads();
  float inv = 1.f / (red[0] + red[1] + red[2] + red[3]);
  uint16_t* pr = pt2 + ((size_t)item * 2500 + (size_t)(s / 48 + 1) * 50 + (s % 48) + 1) * 2304;
  for (int u = 0; u < nact; u++){
    s16x4 w;
#pragma unroll
    for (int i = 0; i < 4; i++) w[i] = (short)f2b(v[u][i] * inv);
    *(s16x4*)&pr[4 * (t + u * 256)] = w;
  }
}

__global__ void k_zero_pad(uint16_t* __restrict__ pt2){
  int p = blockIdx.x, item = blockIdx.y, t = threadIdx.x;
  int sy, sx;
  if (p < 50){ sy = 0; sx = p; }
  else if (p < 100){ sy = 49; sx = p - 50; }
  else if (p < 148){ sy = p - 99; sx = 0; }
  else { sy = p - 147; sx = 49; }
  uint16_t* pr = pt2 + ((size_t)item * 2500 + sy * 50 + sx) * 2304;
  short8 z = {};
  for (int c = t; c < 288; c += 256) *(short8*)&pr[c * 8] = z;
}

// ---------------- raw 4x4 patch bank, layout [item][tap16][co][l] ----------------

__global__ void k_build_rwa(const float* __restrict__ bsrc, uint16_t* __restrict__ rwa){
  __shared__ uint16_t tile[64][66];
  int item = blockIdx.y, l0 = blockIdx.x * 64;
  const float* bp = bsrc + (size_t)item * 64 * 9216;
  int wave = threadIdx.x >> 6, lane = threadIdx.x & 63;
  for (int tap = 0; tap < 16; tap++){
    int py = tap >> 2, qx = tap & 3;
#pragma unroll
    for (int step = 0; step < 16; step++){
      int lsub = wave * 16 + step;
      int l = l0 + lsub, co = lane;
      int m = l * 64 + co;
      int c0 = m / 2304, rem = m % 2304, i = rem / 48, jj = rem % 48;
      int Y = 2 * i + py - 1, X = 2 * jj + qx - 1;
      float val = 0.f;
      if ((unsigned)Y < 96u && (unsigned)X < 96u) val = bp[(size_t)c0 * 9216 + Y * 96 + X];
      tile[lsub][co] = f2b(val);
    }
    __syncthreads();
#pragma unroll
    for (int step = 0; step < 16; step++){
      int co = wave * 16 + step;
      rwa[(((size_t)item * 16 + tap) * 64 + co) * 2304 + l0 + lane] = tile[lane][co];
    }
    __syncthreads();
  }
}

// ---------------- deconv GEMM: T[m=tap*64+co][sp] = Rwa . Pt2^T, M=1024,N=2560,K=2304 ----------------

__launch_bounds__(256)
__global__ void k_deconv2(const uint16_t* __restrict__ rwa, const uint16_t* __restrict__ pt2,
                          uint16_t* __restrict__ T){
  __shared__ __align__(16) uint16_t As[128 * 32];
  __shared__ __align__(16) uint16_t Bs[128 * 32];
  int item = blockIdx.z;
  int n0 = blockIdx.x * 128, m0 = blockIdx.y * 128;
  const uint16_t* Ap = rwa + (size_t)item * 1024 * 2304;
  const uint16_t* Bp = pt2 + (size_t)item * 2500 * 2304;   // rows up to 2559 read garbage; discarded
  int tid = threadIdx.x;
  int wave = tid >> 6, lane = tid & 63, lm = lane & 15, lg = lane >> 4;
  int wy = wave >> 1, wx = wave & 1;
  int swl = (lg ^ ((lm >> 2) & 3)) * 8;
  f32x4 acc[4][4] = {};
  for (int kt = 0; kt < 72; kt++){
    int kb = kt * 32;
#pragma unroll
    for (int c = tid; c < 1024; c += 256){
      int cc = c & 511;
      int row = cc >> 2, j = cc & 3;
      int sw = (j ^ ((row >> 2) & 3)) * 8;
      if (c < 512)
        gl_lds16(&Ap[(size_t)(m0 + row) * 2304 + kb + sw], &As[cc * 8]);
      else
        gl_lds16(&Bp[(size_t)(n0 + row) * 2304 + kb + sw], &Bs[cc * 8]);
    }
    __syncthreads();
    short8 af[4], bf[4];
#pragma unroll
    for (int i = 0; i < 4; i++){
      af[i] = *(const short8*)&As[(wy * 64 + i * 16 + lm) * 32 + swl];
      bf[i] = *(const short8*)&Bs[(wx * 64 + i * 16 + lm) * 32 + swl];
    }
#pragma unroll
    for (int i = 0; i < 4; i++)
#pragma unroll
      for (int j = 0; j < 4; j++)
        acc[i][j] = __builtin_amdgcn_mfma_f32_16x16x32_bf16(af[i], bf[j], acc[i][j], 0, 0, 0);
    __syncthreads();
  }
  uint16_t* Tp = T + (size_t)item * 1024 * 2560;
#pragma unroll
  for (int i = 0; i < 4; i++){
    int rb = m0 + wy * 64 + i * 16 + lg * 4;
#pragma unroll
    for (int j = 0; j < 4; j++){
      int cc = n0 + wx * 64 + j * 16 + lm;
#pragma unroll
      for (int r = 0; r < 4; r++)
        Tp[(size_t)(rb + r) * 2560 + cc] = f2b(acc[i][j][r]);
    }
  }
}

// gather 4 taps per output pixel -> padded Ybt2[98][98][64] interior
__global__ void k_dred2(const uint16_t* __restrict__ T, uint16_t* __restrict__ ybt2){
  int my = blockIdx.x, phase = blockIdx.y, item = blockIdx.z;
  int co = threadIdx.x;
  int fy = phase >> 1, fx = phase & 1;
  const uint16_t* Tp = T + (size_t)item * 1024 * 2560;
  uint16_t* op = ybt2 + (size_t)item * 98 * 98 * 64;
  for (int mx = 0; mx < 48; mx++){
    float acc = 0.f;
#pragma unroll
    for (int ay = 0; ay < 2; ay++)
#pragma unroll
      for (int ax = 0; ax < 2; ax++){
        int tap = (3 - fy - 2 * ay) * 4 + (3 - fx - 2 * ax);
        int sp = (my + ay + fy) * 50 + (mx + ax + fx);
        acc += b2f(Tp[(size_t)(tap * 64 + co) * 2560 + sp]);
      }
    int Y = 2 * my + fy + 1, X = 2 * mx + fx + 1;
    op[((size_t)Y * 98 + X) * 64 + co] = f2b(acc * 0.25f);
  }
}

__global__ void k_zero2(uint16_t* __restrict__ p){
  size_t i = ((size_t)blockIdx.x * 256 + threadIdx.x) * 8;
  short8 z = {};
  *(short8*)&p[i] = z;
}

// ---------------- final 3x3 convs (direct from padded layout) ----------------

// repack w[co][ci][p][q] -> Wp[co][t*64+ci], t=p*3+q
__global__ void k_pack_w(const float* __restrict__ w1, const float* __restrict__ w2,
                         uint16_t* __restrict__ p1, uint16_t* __restrict__ p2){
  int i = blockIdx.x * 256 + threadIdx.x;
  if (i < 36864){
    int co = i / 576, rem = i % 576, ci = rem / 9, t = rem % 9;
    int di = co * 576 + t * 64 + ci;
    p1[di] = f2b(w1[i]); p2[di] = f2b(w2[i]);
  }
}

// C[co][pix] = sum_k Wp[co][k] * Src[(y+py)*98 + x+qx][ci],  k = t*64+ci
__launch_bounds__(256)
__global__ void k_conv_gemm2(const uint16_t* __restrict__ Wp, const uint16_t* __restrict__ Src,
                             const float* __restrict__ bias,
                             uint16_t* __restrict__ dst16, float* __restrict__ dst32){
  __shared__ __align__(16) uint16_t As[64 * 32];
  __shared__ __align__(16) uint16_t Bs[128 * 32];
  int n0 = blockIdx.x * 128, item = blockIdx.z;
  int tid = threadIdx.x, wave = tid >> 6, lane = tid & 63, lm = lane & 15, lg = lane >> 4;
  int swl = (lg ^ ((lm >> 2) & 3)) * 8;
  const uint16_t* Bp = Src + (size_t)item * 98 * 98 * 64;
  f32x4 acc[4][2] = {};
  for (int kt = 0; kt < 18; kt++){
    int t = kt >> 1, cb = (kt & 1) * 32;
    int py = t / 3, qx = t % 3;
#pragma unroll
    for (int c = tid; c < 768; c += 256){
      if (c < 256){
        int row = c >> 2, j = c & 3;
        int sw = (j ^ ((row >> 2) & 3)) * 8;
        gl_lds16(&Wp[(size_t)row * 576 + kt * 32 + sw], &As[c * 8]);
      } else {
        int cc = c - 256; int row = cc >> 2, j = cc & 3;
        int sw = (j ^ ((row >> 2) & 3)) * 8;
        int n = n0 + row; int y = n / 96, x = n % 96;
        gl_lds16(&Bp[((size_t)(y + py) * 98 + (x + qx)) * 64 + cb + sw], &Bs[cc * 8]);
      }
    }
    __syncthreads();
    short8 af[4], bf[2];
#pragma unroll
    for (int i = 0; i < 4; i++) af[i] = *(const short8*)&As[(i * 16 + lm) * 32 + swl];
#pragma unroll
    for (int j = 0; j < 2; j++) bf[j] = *(const short8*)&Bs[(wave * 32 + j * 16 + lm) * 32 + swl];
#pragma unroll
    for (int i = 0; i < 4; i++)
#pragma unroll
      for (int j = 0; j < 2; j++)
        acc[i][j] = __builtin_amdgcn_mfma_f32_16x16x32_bf16(af[i], bf[j], acc[i][j], 0, 0, 0);
    __syncthreads();
  }
  if (dst32){
#pragma unroll
    for (int i = 0; i < 4; i++)
#pragma unroll
      for (int j = 0; j < 2; j++){
        int n = n0 + wave * 32 + j * 16 + lm;
#pragma unroll
        for (int r = 0; r < 4; r++){
          int co = i * 16 + lg * 4 + r;
          dst32[((size_t)item * 64 + co) * 9216 + n] = acc[i][j][r] + bias[co];
        }
      }
  } else {
    uint16_t* dp = dst16 + (size_t)item * 98 * 98 * 64;
#pragma unroll
    for (int i = 0; i < 4; i++)
#pragma unroll
      for (int j = 0; j < 2; j++){
        int n = n0 + wave * 32 + j * 16 + lm;
        int y = n / 96, x = n % 96;
        int co0 = i * 16 + lg * 4;
        s16x4 w;
#pragma unroll
        for (int r = 0; r < 4; r++) w[r] = (short)f2b(acc[i][j][r] + bias[co0 + r]);
        *(s16x4*)&dp[((size_t)(y + 1) * 98 + (x + 1)) * 64 + co0] = w;
      }
  }
}

// ---------------- launch ----------------

extern "C" void kernel_launch(void* const* d_in, const int* in_sizes, int n_in,
                              void* d_out, int out_size, void* d_ws, size_t ws_size,
                              hipStream_t stream){
  const float* f  = (const float*)d_in[0];
  const float* b  = (const float*)d_in[1];
  const float* w1 = (const float*)d_in[2];
  const float* b1 = (const float*)d_in[3];
  const float* w2 = (const float*)d_in[4];
  const float* b2 = (const float*)d_in[5];
  char* ws = (char*)d_ws;
  // region A
  float*    Yt   = (float*)ws;                          // 84,934,656 B (phase1)
  uint16_t* T    = (uint16_t*)ws;                       // 20,971,520 B (over dead Yt)
  uint16_t* Ybt2 = (uint16_t*)(ws + 20971520ull);       //  4,917,248 B
  uint16_t* Y1t2 = (uint16_t*)(ws + 25888768ull);       //  4,917,248 B
  uint16_t* Wp1  = (uint16_t*)(ws + 30806016ull);       //     73,728 B
  uint16_t* Wp2  = (uint16_t*)(ws + 30879744ull);       //     73,728 B
  // region B
  uint16_t* Wn   = (uint16_t*)(ws + SZ_BUF);            // 10,616,832 B (f16 w_hi, stride 576)
  uint16_t* Xb   = Wn + (size_t)4 * 2304 * 576;         // 21,233,664 B (f16 [hi|lo], stride 1152)
  uint16_t* Pt2  = (uint16_t*)(ws + SZ_BUF);            // 46,080,000 B (over dead Wn/Xb)
  uint16_t* Rwa  = (uint16_t*)(ws + SZ_BUF + 46080000ull); // 18,874,368 B
  float*    out  = (float*)d_out;

  k_build_wn<<<dim3(2304, 4), 64, 0, stream>>>(b, Wn);
  k_build_x<<<dim3(2304, 4), 64, 0, stream>>>(f, Xb);
  k_gemm_corr<<<dim3(18, 18, 4), 256, 0, stream>>>(Xb, Wn, Yt);   // A=Xb (1152) -> rows=s
  k_zero_pad<<<dim3(196, 4), 256, 0, stream>>>(Pt2);              // Wn/Xb dead now
  k_build_rwa<<<dim3(36, 4), 256, 0, stream>>>(b, Rwa);
  k_fuse_sm<<<dim3(2304, 4), 256, 0, stream>>>(Yt, Pt2);
  k_deconv2<<<dim3(20, 8, 4), 256, 0, stream>>>(Rwa, Pt2, T);     // Yt dead now
  k_zero2<<<dim3(2401), 256, 0, stream>>>(Ybt2);                  // zeroes Ybt2+Y1t2 (contiguous)
  k_dred2<<<dim3(48, 4, 4), 64, 0, stream>>>(T, Ybt2);
  k_pack_w<<<dim3(144), 256, 0, stream>>>(w1, w2, Wp1, Wp2);
  k_conv_gemm2<<<dim3(72, 1, 4), 256, 0, stream>>>(Wp1, Ybt2, b1, Y1t2, nullptr);
  k_conv_gemm2<<<dim3(72, 1, 4), 256, 0, stream>>>(Wp2, Y1t2, b2, nullptr, out);
}